// Round 1
// baseline (4784.272 us; speedup 1.0000x reference)
//
#include <hip/hip_runtime.h>
#include <hip/hip_bf16.h>
#include <cstddef>

namespace {

constexpr int NB   = 8;     // batch
constexpr int LSEQ = 1025;  // tokens incl. CLS
constexpr int TSEQ = 1024;
constexpr int DM   = 192;   // d_model
constexpr int DI   = 384;   // d_inner
constexpr int DXZ  = 768;   // 2*d_inner
constexpr int DBLW = 140;   // dt_rank + 2*d_state
constexpr int DTR  = 12;    // dt_rank
constexpr int NST  = 64;    // d_state
constexpr int MROWS = NB * LSEQ;  // 8200

__device__ __forceinline__ float waveReduceSum(float v) {
#pragma unroll
  for (int o = 32; o; o >>= 1) v += __shfl_xor(v, o, 64);
  return v;
}

// ---------------- embed ----------------
__global__ void embed_kernel(const int* __restrict__ ids, const float* __restrict__ emb,
                             const float* __restrict__ cls, float* __restrict__ x) {
  int idx = blockIdx.x * blockDim.x + threadIdx.x;   // over NB*LSEQ*DM
  if (idx >= NB * LSEQ * DM) return;
  int d = idx % DM;
  int bt = idx / DM;
  int t = bt % LSEQ, b = bt / LSEQ;
  float v;
  if (t < TSEQ) v = emb[(size_t)ids[b * TSEQ + t] * DM + d];
  else          v = cls[d];
  x[idx] = v;
}

// ---------------- batched transpose: in [Lb][rows][cols] -> out [Lb][cols][rows] ----
__global__ void transpose_batched(const float* __restrict__ in, float* __restrict__ out,
                                  int rows, int cols) {
  __shared__ float tile[32][33];
  int l = blockIdx.z;
  int r0 = blockIdx.y * 32, c0 = blockIdx.x * 32;
  const float* src = in + (size_t)l * rows * cols;
  float* dst = out + (size_t)l * rows * cols;
  int tx = threadIdx.x, ty = threadIdx.y;  // 32 x 8
#pragma unroll
  for (int i = 0; i < 32; i += 8) {
    int r = r0 + ty + i, c = c0 + tx;
    if (r < rows && c < cols) tile[ty + i][tx] = src[(size_t)r * cols + c];
  }
  __syncthreads();
#pragma unroll
  for (int i = 0; i < 32; i += 8) {
    int c = c0 + ty + i, r = r0 + tx;
    if (c < cols && r < rows) dst[(size_t)c * rows + r] = tile[tx][ty + i];
  }
}

// ---------------- rmsnorm (per row of 192) ----------------
__global__ __launch_bounds__(192)
void rmsnorm_kernel(const float* __restrict__ x, const float* __restrict__ w,
                    float* __restrict__ h) {
  int row = blockIdx.x;
  int d = threadIdx.x;
  float v = x[(size_t)row * DM + d];
  float ss = waveReduceSum(v * v);
  __shared__ float red[3];
  if ((d & 63) == 0) red[d >> 6] = ss;
  __syncthreads();
  float ms = (red[0] + red[1] + red[2]) * (1.f / DM);
  h[(size_t)row * DM + d] = v * rsqrtf(ms + 1e-6f) * w[d];
}

// ---------------- generic fp32 GEMM: C[M,N] (+=|=) A[M,K] @ B[K,N] ----------------
// EPI==0: store, EPI==1: C += acc (residual in-place)
template <int EPI>
__global__ __launch_bounds__(256)
void gemm_kernel(const float* __restrict__ A, const float* __restrict__ B,
                 float* C, int M, int N, int K) {
  __shared__ __align__(16) float As[32][68];  // [k][m]
  __shared__ __align__(16) float Bs[32][68];  // [k][n]
  const int tid = threadIdx.x;
  const int row0 = blockIdx.y * 64;
  const int col0 = blockIdx.x * 64;
  const int tm = (tid >> 4) * 4;
  const int tn = (tid & 15) * 4;
  float acc[4][4] = {};
  for (int k0 = 0; k0 < K; k0 += 32) {
    {  // A tile: 64 rows x 32 k ; thread -> (m = tid/4, kk = (tid%4)*8)
      const int m = tid >> 2;
      const int kk = (tid & 3) * 8;
      float4 v0 = make_float4(0, 0, 0, 0), v1 = v0;
      if (row0 + m < M) {
        const float* src = A + (size_t)(row0 + m) * K + k0 + kk;
        v0 = *(const float4*)src;
        v1 = *(const float4*)(src + 4);
      }
      As[kk + 0][m] = v0.x; As[kk + 1][m] = v0.y; As[kk + 2][m] = v0.z; As[kk + 3][m] = v0.w;
      As[kk + 4][m] = v1.x; As[kk + 5][m] = v1.y; As[kk + 6][m] = v1.z; As[kk + 7][m] = v1.w;
    }
    {  // B tile: 32 k x 64 n ; thread -> (kk = tid/8, n = (tid%8)*8)
      const int kk = tid >> 3;
      const int n = (tid & 7) * 8;
      const float* src = B + (size_t)(k0 + kk) * N + col0 + n;
      float v[8];
      if (col0 + n + 8 <= N) {
        float4 v0 = *(const float4*)src;
        float4 v1 = *(const float4*)(src + 4);
        v[0] = v0.x; v[1] = v0.y; v[2] = v0.z; v[3] = v0.w;
        v[4] = v1.x; v[5] = v1.y; v[6] = v1.z; v[7] = v1.w;
      } else {
#pragma unroll
        for (int i = 0; i < 8; ++i) v[i] = (col0 + n + i < N) ? src[i] : 0.f;
      }
#pragma unroll
      for (int i = 0; i < 8; ++i) Bs[kk][n + i] = v[i];
    }
    __syncthreads();
#pragma unroll
    for (int kk = 0; kk < 32; ++kk) {
      float4 av = *(const float4*)&As[kk][tm];
      float4 bv = *(const float4*)&Bs[kk][tn];
      float a[4] = {av.x, av.y, av.z, av.w};
      float b[4] = {bv.x, bv.y, bv.z, bv.w};
#pragma unroll
      for (int i = 0; i < 4; ++i)
#pragma unroll
        for (int j = 0; j < 4; ++j) acc[i][j] = fmaf(a[i], b[j], acc[i][j]);
    }
    __syncthreads();
  }
#pragma unroll
  for (int i = 0; i < 4; ++i) {
    int r = row0 + tm + i;
    if (r >= M) continue;
#pragma unroll
    for (int j = 0; j < 4; ++j) {
      int c = col0 + tn + j;
      if (c >= N) continue;
      size_t idx = (size_t)r * N + c;
      if (EPI == 1) C[idx] += acc[i][j];
      else          C[idx] = acc[i][j];
    }
  }
}

// ---------------- depthwise causal conv3 + bias + silu ----------------
__global__ void conv_kernel(const float* __restrict__ xz, const float* __restrict__ cw,
                            const float* __restrict__ cb, float* __restrict__ xi) {
  int idx = blockIdx.x * blockDim.x + threadIdx.x;  // over NB*LSEQ*DI
  if (idx >= NB * LSEQ * DI) return;
  int c = idx % DI;
  int bt = idx / DI;
  int t = bt % LSEQ, b = bt / LSEQ;
  const float* src = xz + (size_t)b * LSEQ * DXZ + c;  // first half column c
  float s = cb[c];
  float w0 = cw[c * 3 + 0], w1 = cw[c * 3 + 1], w2 = cw[c * 3 + 2];
  if (t >= 2) s = fmaf(w0, src[(size_t)(t - 2) * DXZ], s);
  if (t >= 1) s = fmaf(w1, src[(size_t)(t - 1) * DXZ], s);
  s = fmaf(w2, src[(size_t)t * DXZ], s);
  float sig = 1.f / (1.f + __expf(-s));
  xi[idx] = s * sig;
}

// ---------------- dt = softplus(dt_r @ dtwT + dtb) ----------------
__global__ __launch_bounds__(384)
void dt_kernel(const float* __restrict__ dbl, const float* __restrict__ dtwT,
               const float* __restrict__ dtb, float* __restrict__ dtout) {
  int row = blockIdx.x;   // 0..MROWS-1
  int d = threadIdx.x;    // 0..383
  __shared__ float rr[DTR];
  if (d < DTR) rr[d] = dbl[(size_t)row * DBLW + d];
  __syncthreads();
  float s = dtb[d];
#pragma unroll
  for (int r = 0; r < DTR; ++r) s = fmaf(rr[r], dtwT[r * DI + d], s);
  // stable softplus
  float sp = fmaxf(s, 0.f) + log1pf(__expf(-fabsf(s)));
  dtout[(size_t)row * DI + d] = sp;
}

// ---------------- selective scan + D skip + silu(z) gating ----------------
// one wave per (b, d); lane = state n
__global__ __launch_bounds__(256)
void scan_kernel(const float* __restrict__ dtp_, const float* __restrict__ xi,
                 const float* __restrict__ xz, const float* __restrict__ dbl,
                 const float* __restrict__ Alog, const float* __restrict__ Dpar,
                 float* __restrict__ yg) {
  int wid = (blockIdx.x * blockDim.x + threadIdx.x) >> 6;  // 0..3071
  int lane = threadIdx.x & 63;
  int b = wid / DI, d = wid - b * DI;
  float a = -__expf(Alog[d * NST + lane]);
  float al2 = a * 1.4426950408889634f;  // a * log2(e)
  float Dp = Dpar[d];
  const float* dtp = dtp_ + (size_t)b * LSEQ * DI + d;
  const float* up  = xi   + (size_t)b * LSEQ * DI + d;
  const float* zp  = xz   + (size_t)b * LSEQ * DXZ + DI + d;
  const float* Bp  = dbl  + (size_t)b * LSEQ * DBLW + DTR + lane;
  const float* Cp  = dbl  + (size_t)b * LSEQ * DBLW + DTR + NST + lane;
  float* yp = yg + (size_t)b * LSEQ * DI + d;
  float h = 0.f;
  float dtv = *dtp, uv = *up, zv = *zp, Bv = *Bp, Cv = *Cp;
  for (int t = 0; t < LSEQ; ++t) {
    float n_dt = 0.f, n_u = 0.f, n_z = 0.f, n_B = 0.f, n_C = 0.f;
    if (t + 1 < LSEQ) {
      dtp += DI; up += DI; zp += DXZ; Bp += DBLW; Cp += DBLW;
      n_dt = *dtp; n_u = *up; n_z = *zp; n_B = *Bp; n_C = *Cp;
    }
    float dA = exp2f(dtv * al2);
    h = fmaf(dA, h, dtv * uv * Bv);
    float p = waveReduceSum(h * Cv);
    float sig = 1.f / (1.f + __expf(-zv));
    float out = (p + uv * Dp) * (zv * sig);
    if (lane == 0) *yp = out;
    yp += DI;
    dtv = n_dt; uv = n_u; zv = n_z; Bv = n_B; Cv = n_C;
  }
}

// ---------------- final norm + masked mean pool (two stage) + head ------------
__global__ __launch_bounds__(192)
void pool1_kernel(const float* __restrict__ x, const int* __restrict__ mask,
                  const float* __restrict__ fw, float* __restrict__ partial) {
  int b = blockIdx.x >> 6;      // grid = 8*64
  int chunk = blockIdx.x & 63;
  int d = threadIdx.x;          // 0..191
  __shared__ float red[3];
  float w = fw[d];
  float acc = 0.f;
  for (int tt = 0; tt < 16; ++tt) {
    int t = chunk * 16 + tt;    // < 1024 always
    float v = x[((size_t)b * LSEQ + t) * DM + d];
    float ss = waveReduceSum(v * v);
    if ((d & 63) == 0) red[d >> 6] = ss;
    __syncthreads();
    float ms = (red[0] + red[1] + red[2]) * (1.f / DM);
    float m = (float)mask[b * TSEQ + t];
    acc = fmaf(v * rsqrtf(ms + 1e-6f) * w, m, acc);
    __syncthreads();
  }
  partial[((size_t)b * 64 + chunk) * DM + d] = acc;
}

__global__ __launch_bounds__(192)
void pool2_kernel(const float* __restrict__ partial, const int* __restrict__ mask,
                  const float* __restrict__ hw, const float* __restrict__ hb,
                  float* __restrict__ out) {
  int b = blockIdx.x;
  int d = threadIdx.x;
  float s = 0.f;
  for (int c = 0; c < 64; ++c) s += partial[((size_t)b * 64 + c) * DM + d];
  float den = 0.f;
  for (int t = d; t < TSEQ; t += DM) den += (float)mask[b * TSEQ + t];
  den = waveReduceSum(den);
  __shared__ float dred[3];
  __shared__ float pooled[DM];
  if ((d & 63) == 0) dred[d >> 6] = den;
  __syncthreads();
  float denom = fmaxf(dred[0] + dred[1] + dred[2], 1.f);
  pooled[d] = s / denom;
  __syncthreads();
  if (d < 2) {
    float acc = hb[d];
    for (int k = 0; k < DM; ++k) acc = fmaf(pooled[k], hw[d * DM + k], acc);
    out[b * 2 + d] = acc;
  }
}

}  // namespace

extern "C" void kernel_launch(void* const* d_in, const int* in_sizes, int n_in,
                              void* d_out, int out_size, void* d_ws, size_t ws_size,
                              hipStream_t stream) {
  const int*   ids    = (const int*)d_in[0];
  const int*   mask   = (const int*)d_in[1];
  const float* embed  = (const float*)d_in[2];
  const float* cls    = (const float*)d_in[3];
  const float* norm_w = (const float*)d_in[4];
  const float* in_w   = (const float*)d_in[5];
  const float* conv_w = (const float*)d_in[6];
  const float* conv_b = (const float*)d_in[7];
  const float* xp_w   = (const float*)d_in[8];
  const float* dtw    = (const float*)d_in[9];
  const float* dtb    = (const float*)d_in[10];
  const float* Alog   = (const float*)d_in[11];
  const float* Dpar   = (const float*)d_in[12];
  const float* ow     = (const float*)d_in[13];
  const float* fnw    = (const float*)d_in[14];
  const float* hw     = (const float*)d_in[15];
  const float* hb     = (const float*)d_in[16];
  float* out = (float*)d_out;

  float* ws = (float*)d_ws;
  size_t off = 0;
  float* x      = ws + off; off += (size_t)NB * LSEQ * DM;    // 1,574,400
  float* h      = ws + off; off += (size_t)NB * LSEQ * DM;
  float* xz     = ws + off; off += (size_t)NB * LSEQ * DXZ;   // 6,297,600
  float* xi     = ws + off; off += (size_t)NB * LSEQ * DI;
  float* dblb   = ws + off; off += (size_t)NB * LSEQ * DBLW;
  float* dtbuf  = ws + off; off += (size_t)NB * LSEQ * DI;
  float* yg     = ws + off; off += (size_t)NB * LSEQ * DI;
  float* wT_in  = ws + off; off += (size_t)8 * DM * DXZ;      // 192x768 per layer
  float* wT_xp  = ws + off; off += (size_t)8 * DI * DBLW;     // 384x140
  float* wT_dt  = ws + off; off += (size_t)8 * DTR * DI;      // 12x384
  float* wT_ow  = ws + off; off += (size_t)8 * DI * DM;       // 384x192
  float* partial = ws + off; off += (size_t)NB * 64 * DM;     // pool partials

  dim3 tb(32, 8);
  // in_w (768,192) -> (192,768)
  transpose_batched<<<dim3(6, 24, 8), tb, 0, stream>>>(in_w, wT_in, DXZ, DM);
  // xp_w (140,384) -> (384,140)
  transpose_batched<<<dim3(12, 5, 8), tb, 0, stream>>>(xp_w, wT_xp, DBLW, DI);
  // dtw (384,12) -> (12,384)
  transpose_batched<<<dim3(1, 12, 8), tb, 0, stream>>>(dtw, wT_dt, DI, DTR);
  // ow (192,384) -> (384,192)
  transpose_batched<<<dim3(12, 6, 8), tb, 0, stream>>>(ow, wT_ow, DM, DI);

  embed_kernel<<<(NB * LSEQ * DM) / 256, 256, 0, stream>>>(ids, embed, cls, x);

  for (int l = 0; l < 8; ++l) {
    rmsnorm_kernel<<<MROWS, 192, 0, stream>>>(x, norm_w + l * DM, h);
    gemm_kernel<0><<<dim3(DXZ / 64, (MROWS + 63) / 64), 256, 0, stream>>>(
        h, wT_in + (size_t)l * DM * DXZ, xz, MROWS, DXZ, DM);
    conv_kernel<<<(NB * LSEQ * DI) / 256, 256, 0, stream>>>(
        xz, conv_w + l * DI * 3, conv_b + l * DI, xi);
    gemm_kernel<0><<<dim3((DBLW + 63) / 64, (MROWS + 63) / 64), 256, 0, stream>>>(
        xi, wT_xp + (size_t)l * DI * DBLW, dblb, MROWS, DBLW, DI);
    dt_kernel<<<MROWS, DI, 0, stream>>>(dblb, wT_dt + l * DTR * DI, dtb + l * DI, dtbuf);
    scan_kernel<<<(NB * DI) / 4, 256, 0, stream>>>(
        dtbuf, xi, xz, dblb, Alog + (size_t)l * DI * NST, Dpar + l * DI, yg);
    gemm_kernel<1><<<dim3(DM / 64, (MROWS + 63) / 64), 256, 0, stream>>>(
        yg, wT_ow + (size_t)l * DI * DM, x, MROWS, DM, DI);
  }

  pool1_kernel<<<NB * 64, 192, 0, stream>>>(x, mask, fnw, partial);
  pool2_kernel<<<NB, 192, 0, stream>>>(partial, mask, hw, hb, out);
}

// Round 2
// 3676.594 us; speedup vs baseline: 1.3013x; 1.3013x over previous
//
#include <hip/hip_runtime.h>
#include <hip/hip_bf16.h>
#include <cstddef>

namespace {

constexpr int NB   = 8;     // batch
constexpr int LSEQ = 1025;  // tokens incl. CLS
constexpr int TSEQ = 1024;
constexpr int DM   = 192;   // d_model
constexpr int DI   = 384;   // d_inner
constexpr int DXZ  = 768;   // 2*d_inner
constexpr int DBLW = 140;   // dt_rank + 2*d_state
constexpr int DTR  = 12;    // dt_rank
constexpr int NST  = 64;    // d_state
constexpr int MROWS = NB * LSEQ;  // 8200
constexpr int NCH  = 16;    // scan chunks
constexpr int CS   = 64;    // chunk size (last chunk = 65)
constexpr int NCH1 = NCH - 1;

__device__ __forceinline__ float waveReduceSum(float v) {
#pragma unroll
  for (int o = 32; o; o >>= 1) v += __shfl_xor(v, o, 64);
  return v;
}

// ---------------- embed ----------------
__global__ void embed_kernel(const int* __restrict__ ids, const float* __restrict__ emb,
                             const float* __restrict__ cls, float* __restrict__ x) {
  int idx = blockIdx.x * blockDim.x + threadIdx.x;   // over NB*LSEQ*DM
  if (idx >= NB * LSEQ * DM) return;
  int d = idx % DM;
  int bt = idx / DM;
  int t = bt % LSEQ, b = bt / LSEQ;
  float v;
  if (t < TSEQ) v = emb[(size_t)ids[b * TSEQ + t] * DM + d];
  else          v = cls[d];
  x[idx] = v;
}

// ---------------- batched transpose: in [Lb][rows][cols] -> out [Lb][cols][rows] ----
__global__ void transpose_batched(const float* __restrict__ in, float* __restrict__ out,
                                  int rows, int cols) {
  __shared__ float tile[32][33];
  int l = blockIdx.z;
  int r0 = blockIdx.y * 32, c0 = blockIdx.x * 32;
  const float* src = in + (size_t)l * rows * cols;
  float* dst = out + (size_t)l * rows * cols;
  int tx = threadIdx.x, ty = threadIdx.y;  // 32 x 8
#pragma unroll
  for (int i = 0; i < 32; i += 8) {
    int r = r0 + ty + i, c = c0 + tx;
    if (r < rows && c < cols) tile[ty + i][tx] = src[(size_t)r * cols + c];
  }
  __syncthreads();
#pragma unroll
  for (int i = 0; i < 32; i += 8) {
    int c = c0 + ty + i, r = r0 + tx;
    if (c < cols && r < rows) dst[(size_t)c * rows + r] = tile[tx][ty + i];
  }
}

// ---------------- rmsnorm (per row of 192) ----------------
__global__ __launch_bounds__(192)
void rmsnorm_kernel(const float* __restrict__ x, const float* __restrict__ w,
                    float* __restrict__ h) {
  int row = blockIdx.x;
  int d = threadIdx.x;
  float v = x[(size_t)row * DM + d];
  float ss = waveReduceSum(v * v);
  __shared__ float red[3];
  if ((d & 63) == 0) red[d >> 6] = ss;
  __syncthreads();
  float ms = (red[0] + red[1] + red[2]) * (1.f / DM);
  h[(size_t)row * DM + d] = v * rsqrtf(ms + 1e-6f) * w[d];
}

// ---------------- generic fp32 GEMM: C[M,N] (+=|=) A[M,K] @ B[K,N] ----------------
template <int EPI>
__global__ __launch_bounds__(256)
void gemm_kernel(const float* __restrict__ A, const float* __restrict__ B,
                 float* C, int M, int N, int K) {
  __shared__ __align__(16) float As[32][68];  // [k][m]
  __shared__ __align__(16) float Bs[32][68];  // [k][n]
  const int tid = threadIdx.x;
  const int row0 = blockIdx.y * 64;
  const int col0 = blockIdx.x * 64;
  const int tm = (tid >> 4) * 4;
  const int tn = (tid & 15) * 4;
  float acc[4][4] = {};
  for (int k0 = 0; k0 < K; k0 += 32) {
    {  // A tile
      const int m = tid >> 2;
      const int kk = (tid & 3) * 8;
      float4 v0 = make_float4(0, 0, 0, 0), v1 = v0;
      if (row0 + m < M) {
        const float* src = A + (size_t)(row0 + m) * K + k0 + kk;
        v0 = *(const float4*)src;
        v1 = *(const float4*)(src + 4);
      }
      As[kk + 0][m] = v0.x; As[kk + 1][m] = v0.y; As[kk + 2][m] = v0.z; As[kk + 3][m] = v0.w;
      As[kk + 4][m] = v1.x; As[kk + 5][m] = v1.y; As[kk + 6][m] = v1.z; As[kk + 7][m] = v1.w;
    }
    {  // B tile
      const int kk = tid >> 3;
      const int n = (tid & 7) * 8;
      const float* src = B + (size_t)(k0 + kk) * N + col0 + n;
      float v[8];
      if (col0 + n + 8 <= N) {
        float4 v0 = *(const float4*)src;
        float4 v1 = *(const float4*)(src + 4);
        v[0] = v0.x; v[1] = v0.y; v[2] = v0.z; v[3] = v0.w;
        v[4] = v1.x; v[5] = v1.y; v[6] = v1.z; v[7] = v1.w;
      } else {
#pragma unroll
        for (int i = 0; i < 8; ++i) v[i] = (col0 + n + i < N) ? src[i] : 0.f;
      }
#pragma unroll
      for (int i = 0; i < 8; ++i) Bs[kk][n + i] = v[i];
    }
    __syncthreads();
#pragma unroll
    for (int kk = 0; kk < 32; ++kk) {
      float4 av = *(const float4*)&As[kk][tm];
      float4 bv = *(const float4*)&Bs[kk][tn];
      float a[4] = {av.x, av.y, av.z, av.w};
      float b[4] = {bv.x, bv.y, bv.z, bv.w};
#pragma unroll
      for (int i = 0; i < 4; ++i)
#pragma unroll
        for (int j = 0; j < 4; ++j) acc[i][j] = fmaf(a[i], b[j], acc[i][j]);
    }
    __syncthreads();
  }
#pragma unroll
  for (int i = 0; i < 4; ++i) {
    int r = row0 + tm + i;
    if (r >= M) continue;
#pragma unroll
    for (int j = 0; j < 4; ++j) {
      int c = col0 + tn + j;
      if (c >= N) continue;
      size_t idx = (size_t)r * N + c;
      if (EPI == 1) C[idx] += acc[i][j];
      else          C[idx] = acc[i][j];
    }
  }
}

// ------- depthwise causal conv3 + bias + silu, AND zg = silu(z) for gate -------
__global__ void conv_kernel(const float* __restrict__ xz, const float* __restrict__ cw,
                            const float* __restrict__ cb, float* __restrict__ xi,
                            float* __restrict__ zg) {
  int idx = blockIdx.x * blockDim.x + threadIdx.x;  // over NB*LSEQ*DI
  if (idx >= NB * LSEQ * DI) return;
  int c = idx % DI;
  int bt = idx / DI;
  int t = bt % LSEQ, b = bt / LSEQ;
  const float* src = xz + (size_t)b * LSEQ * DXZ + c;  // first half column c
  float s = cb[c];
  float w0 = cw[c * 3 + 0], w1 = cw[c * 3 + 1], w2 = cw[c * 3 + 2];
  if (t >= 2) s = fmaf(w0, src[(size_t)(t - 2) * DXZ], s);
  if (t >= 1) s = fmaf(w1, src[(size_t)(t - 1) * DXZ], s);
  s = fmaf(w2, src[(size_t)t * DXZ], s);
  float sig = 1.f / (1.f + __expf(-s));
  xi[idx] = s * sig;
  // gate: z = xz[b,t,DI+c]
  float zv = src[(size_t)t * DXZ + DI];
  float zsig = 1.f / (1.f + __expf(-zv));
  zg[idx] = zv * zsig;
}

// ---------------- dt = softplus(dt_r @ dtwT + dtb) ----------------
__global__ __launch_bounds__(384)
void dt_kernel(const float* __restrict__ dbl, const float* __restrict__ dtwT,
               const float* __restrict__ dtb, float* __restrict__ dtout) {
  int row = blockIdx.x;   // 0..MROWS-1
  int d = threadIdx.x;    // 0..383
  __shared__ float rr[DTR];
  if (d < DTR) rr[d] = dbl[(size_t)row * DBLW + d];
  __syncthreads();
  float s = dtb[d];
#pragma unroll
  for (int r = 0; r < DTR; ++r) s = fmaf(rr[r], dtwT[r * DI + d], s);
  float sp = fmaxf(s, 0.f) + log1pf(__expf(-fabsf(s)));
  dtout[(size_t)row * DI + d] = sp;
}

// ======== chunked selective scan ========
// pass1: per (b,d,chunk c<15): local scan from h=0 -> aprod[n], hend[n]
__global__ __launch_bounds__(256)
void scan_pass1(const float* __restrict__ dtp_, const float* __restrict__ xi,
                const float* __restrict__ dbl, const float* __restrict__ Alog,
                float* __restrict__ aprod_out, float* __restrict__ hend_out) {
  int wid = (blockIdx.x * blockDim.x + threadIdx.x) >> 6;  // 0 .. 3072*15-1
  int lane = threadIdx.x & 63;
  int c = wid % NCH1;
  int bd = wid / NCH1;
  int b = bd / DI, d = bd - b * DI;
  int t0 = c * CS;
  float a = -__expf(Alog[d * NST + lane]);
  float al2 = a * 1.4426950408889634f;
  const float* dtp = dtp_ + ((size_t)b * LSEQ + t0) * DI + d;
  const float* up  = xi   + ((size_t)b * LSEQ + t0) * DI + d;
  const float* Bp  = dbl  + ((size_t)b * LSEQ + t0) * DBLW + DTR + lane;
  float h = 0.f, ap = 1.f;
  float dtv = *dtp, uv = *up, Bv = *Bp;
#pragma unroll 4
  for (int t = 0; t < CS; ++t) {
    float n_dt = 0.f, n_u = 0.f, n_B = 0.f;
    if (t + 1 < CS) {
      dtp += DI; up += DI; Bp += DBLW;
      n_dt = *dtp; n_u = *up; n_B = *Bp;
    }
    float dA = exp2f(dtv * al2);
    h = fmaf(dA, h, dtv * uv * Bv);
    ap *= dA;
    dtv = n_dt; uv = n_u; Bv = n_B;
  }
  size_t oidx = ((size_t)bd * NCH1 + c) * NST + lane;
  aprod_out[oidx] = ap;
  hend_out[oidx] = h;
}

// pass2: sequential combine over chunks -> hinit[b,d,c,n]
__global__ __launch_bounds__(256)
void scan_pass2(const float* __restrict__ aprod, const float* __restrict__ hend,
                float* __restrict__ hinit) {
  int wid = (blockIdx.x * blockDim.x + threadIdx.x) >> 6;  // over b*DI = 3072
  int lane = threadIdx.x & 63;
  size_t base15 = (size_t)wid * NCH1 * NST + lane;
  size_t base16 = (size_t)wid * NCH * NST + lane;
  float h = 0.f;
#pragma unroll
  for (int c = 0; c < NCH; ++c) {
    hinit[base16 + (size_t)c * NST] = h;
    if (c < NCH1) {
      size_t i = base15 + (size_t)c * NST;
      h = fmaf(aprod[i], h, hend[i]);
    }
  }
}

// pass3: per (b,d,chunk): scan from hinit, y = (C.h + u*D)*zg, store lane0
__global__ __launch_bounds__(256)
void scan_pass3(const float* __restrict__ dtp_, const float* __restrict__ xi,
                const float* __restrict__ zg, const float* __restrict__ dbl,
                const float* __restrict__ Alog, const float* __restrict__ Dpar,
                const float* __restrict__ hinit, float* __restrict__ yg) {
  int wid = (blockIdx.x * blockDim.x + threadIdx.x) >> 6;  // 0 .. 3072*16-1
  int lane = threadIdx.x & 63;
  int c = wid & (NCH - 1);
  int bd = wid >> 4;
  int b = bd / DI, d = bd - b * DI;
  int t0 = c * CS;
  int nsteps = (c == NCH - 1) ? (LSEQ - t0) : CS;
  float a = -__expf(Alog[d * NST + lane]);
  float al2 = a * 1.4426950408889634f;
  float Dp = Dpar[d];
  const float* dtp = dtp_ + ((size_t)b * LSEQ + t0) * DI + d;
  const float* up  = xi   + ((size_t)b * LSEQ + t0) * DI + d;
  const float* gp  = zg   + ((size_t)b * LSEQ + t0) * DI + d;
  const float* Bp  = dbl  + ((size_t)b * LSEQ + t0) * DBLW + DTR + lane;
  const float* Cp  = dbl  + ((size_t)b * LSEQ + t0) * DBLW + DTR + NST + lane;
  float* yp = yg + ((size_t)b * LSEQ + t0) * DI + d;
  float h = hinit[((size_t)bd * NCH + c) * NST + lane];
  float dtv = *dtp, uv = *up, gv = *gp, Bv = *Bp, Cv = *Cp;
  for (int t = 0; t < nsteps; ++t) {
    float n_dt = 0.f, n_u = 0.f, n_g = 0.f, n_B = 0.f, n_C = 0.f;
    if (t + 1 < nsteps) {
      dtp += DI; up += DI; gp += DI; Bp += DBLW; Cp += DBLW;
      n_dt = *dtp; n_u = *up; n_g = *gp; n_B = *Bp; n_C = *Cp;
    }
    float dA = exp2f(dtv * al2);
    h = fmaf(dA, h, dtv * uv * Bv);
    float p = waveReduceSum(h * Cv);
    float out = fmaf(uv, Dp, p) * gv;
    if (lane == 0) *yp = out;
    yp += DI;
    dtv = n_dt; uv = n_u; gv = n_g; Bv = n_B; Cv = n_C;
  }
}

// ---------------- final norm + masked mean pool (two stage) + head ------------
__global__ __launch_bounds__(192)
void pool1_kernel(const float* __restrict__ x, const int* __restrict__ mask,
                  const float* __restrict__ fw, float* __restrict__ partial) {
  int b = blockIdx.x >> 6;      // grid = 8*64
  int chunk = blockIdx.x & 63;
  int d = threadIdx.x;          // 0..191
  __shared__ float red[3];
  float w = fw[d];
  float acc = 0.f;
  for (int tt = 0; tt < 16; ++tt) {
    int t = chunk * 16 + tt;    // < 1024 always
    float v = x[((size_t)b * LSEQ + t) * DM + d];
    float ss = waveReduceSum(v * v);
    if ((d & 63) == 0) red[d >> 6] = ss;
    __syncthreads();
    float ms = (red[0] + red[1] + red[2]) * (1.f / DM);
    float m = (float)mask[b * TSEQ + t];
    acc = fmaf(v * rsqrtf(ms + 1e-6f) * w, m, acc);
    __syncthreads();
  }
  partial[((size_t)b * 64 + chunk) * DM + d] = acc;
}

__global__ __launch_bounds__(192)
void pool2_kernel(const float* __restrict__ partial, const int* __restrict__ mask,
                  const float* __restrict__ hw, const float* __restrict__ hb,
                  float* __restrict__ out) {
  int b = blockIdx.x;
  int d = threadIdx.x;
  float s = 0.f;
  for (int c = 0; c < 64; ++c) s += partial[((size_t)b * 64 + c) * DM + d];
  float den = 0.f;
  for (int t = d; t < TSEQ; t += DM) den += (float)mask[b * TSEQ + t];
  den = waveReduceSum(den);
  __shared__ float dred[3];
  __shared__ float pooled[DM];
  if ((d & 63) == 0) dred[d >> 6] = den;
  __syncthreads();
  float denom = fmaxf(dred[0] + dred[1] + dred[2], 1.f);
  pooled[d] = s / denom;
  __syncthreads();
  if (d < 2) {
    float acc = hb[d];
    for (int k = 0; k < DM; ++k) acc = fmaf(pooled[k], hw[d * DM + k], acc);
    out[b * 2 + d] = acc;
  }
}

}  // namespace

extern "C" void kernel_launch(void* const* d_in, const int* in_sizes, int n_in,
                              void* d_out, int out_size, void* d_ws, size_t ws_size,
                              hipStream_t stream) {
  const int*   ids    = (const int*)d_in[0];
  const int*   mask   = (const int*)d_in[1];
  const float* embed  = (const float*)d_in[2];
  const float* cls    = (const float*)d_in[3];
  const float* norm_w = (const float*)d_in[4];
  const float* in_w   = (const float*)d_in[5];
  const float* conv_w = (const float*)d_in[6];
  const float* conv_b = (const float*)d_in[7];
  const float* xp_w   = (const float*)d_in[8];
  const float* dtw    = (const float*)d_in[9];
  const float* dtb    = (const float*)d_in[10];
  const float* Alog   = (const float*)d_in[11];
  const float* Dpar   = (const float*)d_in[12];
  const float* ow     = (const float*)d_in[13];
  const float* fnw    = (const float*)d_in[14];
  const float* hw     = (const float*)d_in[15];
  const float* hb     = (const float*)d_in[16];
  float* out = (float*)d_out;

  float* ws = (float*)d_ws;
  size_t off = 0;
  float* x      = ws + off; off += (size_t)NB * LSEQ * DM;
  float* h      = ws + off; off += (size_t)NB * LSEQ * DM;
  float* xz     = ws + off; off += (size_t)NB * LSEQ * DXZ;
  float* xi     = ws + off; off += (size_t)NB * LSEQ * DI;
  float* zgbuf  = ws + off; off += (size_t)NB * LSEQ * DI;
  float* dblb   = ws + off; off += (size_t)NB * LSEQ * DBLW;
  float* dtbuf  = ws + off; off += (size_t)NB * LSEQ * DI;
  float* yg     = ws + off; off += (size_t)NB * LSEQ * DI;
  float* wT_in  = ws + off; off += (size_t)8 * DM * DXZ;
  float* wT_xp  = ws + off; off += (size_t)8 * DI * DBLW;
  float* wT_dt  = ws + off; off += (size_t)8 * DTR * DI;
  float* wT_ow  = ws + off; off += (size_t)8 * DI * DM;
  float* partial = ws + off; off += (size_t)NB * 64 * DM;
  float* aprod  = ws + off; off += (size_t)NB * DI * NCH1 * NST;  // 2.95M
  float* hend   = ws + off; off += (size_t)NB * DI * NCH1 * NST;
  float* hinit  = ws + off; off += (size_t)NB * DI * NCH * NST;   // 3.15M

  dim3 tb(32, 8);
  transpose_batched<<<dim3(6, 24, 8), tb, 0, stream>>>(in_w, wT_in, DXZ, DM);
  transpose_batched<<<dim3(12, 5, 8), tb, 0, stream>>>(xp_w, wT_xp, DBLW, DI);
  transpose_batched<<<dim3(1, 12, 8), tb, 0, stream>>>(dtw, wT_dt, DI, DTR);
  transpose_batched<<<dim3(12, 6, 8), tb, 0, stream>>>(ow, wT_ow, DM, DI);

  embed_kernel<<<(NB * LSEQ * DM) / 256, 256, 0, stream>>>(ids, embed, cls, x);

  for (int l = 0; l < 8; ++l) {
    rmsnorm_kernel<<<MROWS, 192, 0, stream>>>(x, norm_w + l * DM, h);
    gemm_kernel<0><<<dim3(DXZ / 64, (MROWS + 63) / 64), 256, 0, stream>>>(
        h, wT_in + (size_t)l * DM * DXZ, xz, MROWS, DXZ, DM);
    conv_kernel<<<(NB * LSEQ * DI) / 256, 256, 0, stream>>>(
        xz, conv_w + l * DI * 3, conv_b + l * DI, xi, zgbuf);
    gemm_kernel<0><<<dim3((DBLW + 63) / 64, (MROWS + 63) / 64), 256, 0, stream>>>(
        xi, wT_xp + (size_t)l * DI * DBLW, dblb, MROWS, DBLW, DI);
    dt_kernel<<<MROWS, DI, 0, stream>>>(dblb, wT_dt + l * DTR * DI, dtb + l * DI, dtbuf);
    // chunked scan
    scan_pass1<<<(NB * DI * NCH1) / 4, 256, 0, stream>>>(
        dtbuf, xi, dblb, Alog + (size_t)l * DI * NST, aprod, hend);
    scan_pass2<<<(NB * DI) / 4, 256, 0, stream>>>(aprod, hend, hinit);
    scan_pass3<<<(NB * DI * NCH) / 4, 256, 0, stream>>>(
        dtbuf, xi, zgbuf, dblb, Alog + (size_t)l * DI * NST, Dpar + l * DI, hinit, yg);
    gemm_kernel<1><<<dim3(DM / 64, (MROWS + 63) / 64), 256, 0, stream>>>(
        yg, wT_ow + (size_t)l * DI * DM, x, MROWS, DM, DI);
  }

  pool1_kernel<<<NB * 64, 192, 0, stream>>>(x, mask, fnw, partial);
  pool2_kernel<<<NB, 192, 0, stream>>>(partial, mask, hw, hb, out);
}

// Round 3
// 2799.050 us; speedup vs baseline: 1.7092x; 1.3135x over previous
//
#include <hip/hip_runtime.h>
#include <hip/hip_bf16.h>
#include <cstddef>

namespace {

constexpr int NB   = 8;     // batch
constexpr int LSEQ = 1025;  // tokens incl. CLS
constexpr int TSEQ = 1024;
constexpr int DM   = 192;   // d_model
constexpr int DI   = 384;   // d_inner
constexpr int DXZ  = 768;   // 2*d_inner
constexpr int DBLW = 140;   // dt_rank + 2*d_state
constexpr int DTR  = 12;    // dt_rank
constexpr int NST  = 64;    // d_state
constexpr int MROWS = NB * LSEQ;  // 8200
constexpr int NCH  = 32;    // scan chunks
constexpr int CS   = 32;    // chunk size (last chunk = 33)
constexpr int NCH1 = NCH - 1;
constexpr int NDG  = DI / 64;  // 6 channel groups
constexpr float LOG2E = 1.4426950408889634f;

__device__ __forceinline__ float waveReduceSum(float v) {
#pragma unroll
  for (int o = 32; o; o >>= 1) v += __shfl_xor(v, o, 64);
  return v;
}

__device__ __forceinline__ float rdlane(float v, int n) {
  return __int_as_float(__builtin_amdgcn_readlane(__float_as_int(v), n));
}

// ---------------- embed ----------------
__global__ void embed_kernel(const int* __restrict__ ids, const float* __restrict__ emb,
                             const float* __restrict__ cls, float* __restrict__ x) {
  int idx = blockIdx.x * blockDim.x + threadIdx.x;   // over NB*LSEQ*DM
  if (idx >= NB * LSEQ * DM) return;
  int d = idx % DM;
  int bt = idx / DM;
  int t = bt % LSEQ, b = bt / LSEQ;
  float v;
  if (t < TSEQ) v = emb[(size_t)ids[b * TSEQ + t] * DM + d];
  else          v = cls[d];
  x[idx] = v;
}

// ---------------- batched transpose ----------------
__global__ void transpose_batched(const float* __restrict__ in, float* __restrict__ out,
                                  int rows, int cols) {
  __shared__ float tile[32][33];
  int l = blockIdx.z;
  int r0 = blockIdx.y * 32, c0 = blockIdx.x * 32;
  const float* src = in + (size_t)l * rows * cols;
  float* dst = out + (size_t)l * rows * cols;
  int tx = threadIdx.x, ty = threadIdx.y;  // 32 x 8
#pragma unroll
  for (int i = 0; i < 32; i += 8) {
    int r = r0 + ty + i, c = c0 + tx;
    if (r < rows && c < cols) tile[ty + i][tx] = src[(size_t)r * cols + c];
  }
  __syncthreads();
#pragma unroll
  for (int i = 0; i < 32; i += 8) {
    int c = c0 + ty + i, r = r0 + tx;
    if (c < cols && r < rows) dst[(size_t)c * rows + r] = tile[tx][ty + i];
  }
}

// ---------------- rmsnorm ----------------
__global__ __launch_bounds__(192)
void rmsnorm_kernel(const float* __restrict__ x, const float* __restrict__ w,
                    float* __restrict__ h) {
  int row = blockIdx.x;
  int d = threadIdx.x;
  float v = x[(size_t)row * DM + d];
  float ss = waveReduceSum(v * v);
  __shared__ float red[3];
  if ((d & 63) == 0) red[d >> 6] = ss;
  __syncthreads();
  float ms = (red[0] + red[1] + red[2]) * (1.f / DM);
  h[(size_t)row * DM + d] = v * rsqrtf(ms + 1e-6f) * w[d];
}

// ---------------- generic fp32 GEMM ----------------
template <int EPI>
__global__ __launch_bounds__(256)
void gemm_kernel(const float* __restrict__ A, const float* __restrict__ B,
                 float* C, int M, int N, int K) {
  __shared__ __align__(16) float As[32][68];
  __shared__ __align__(16) float Bs[32][68];
  const int tid = threadIdx.x;
  const int row0 = blockIdx.y * 64;
  const int col0 = blockIdx.x * 64;
  const int tm = (tid >> 4) * 4;
  const int tn = (tid & 15) * 4;
  float acc[4][4] = {};
  for (int k0 = 0; k0 < K; k0 += 32) {
    {
      const int m = tid >> 2;
      const int kk = (tid & 3) * 8;
      float4 v0 = make_float4(0, 0, 0, 0), v1 = v0;
      if (row0 + m < M) {
        const float* src = A + (size_t)(row0 + m) * K + k0 + kk;
        v0 = *(const float4*)src;
        v1 = *(const float4*)(src + 4);
      }
      As[kk + 0][m] = v0.x; As[kk + 1][m] = v0.y; As[kk + 2][m] = v0.z; As[kk + 3][m] = v0.w;
      As[kk + 4][m] = v1.x; As[kk + 5][m] = v1.y; As[kk + 6][m] = v1.z; As[kk + 7][m] = v1.w;
    }
    {
      const int kk = tid >> 3;
      const int n = (tid & 7) * 8;
      const float* src = B + (size_t)(k0 + kk) * N + col0 + n;
      float v[8];
      if (col0 + n + 8 <= N) {
        float4 v0 = *(const float4*)src;
        float4 v1 = *(const float4*)(src + 4);
        v[0] = v0.x; v[1] = v0.y; v[2] = v0.z; v[3] = v0.w;
        v[4] = v1.x; v[5] = v1.y; v[6] = v1.z; v[7] = v1.w;
      } else {
#pragma unroll
        for (int i = 0; i < 8; ++i) v[i] = (col0 + n + i < N) ? src[i] : 0.f;
      }
#pragma unroll
      for (int i = 0; i < 8; ++i) Bs[kk][n + i] = v[i];
    }
    __syncthreads();
#pragma unroll
    for (int kk = 0; kk < 32; ++kk) {
      float4 av = *(const float4*)&As[kk][tm];
      float4 bv = *(const float4*)&Bs[kk][tn];
      float a[4] = {av.x, av.y, av.z, av.w};
      float b[4] = {bv.x, bv.y, bv.z, bv.w};
#pragma unroll
      for (int i = 0; i < 4; ++i)
#pragma unroll
        for (int j = 0; j < 4; ++j) acc[i][j] = fmaf(a[i], b[j], acc[i][j]);
    }
    __syncthreads();
  }
#pragma unroll
  for (int i = 0; i < 4; ++i) {
    int r = row0 + tm + i;
    if (r >= M) continue;
#pragma unroll
    for (int j = 0; j < 4; ++j) {
      int c = col0 + tn + j;
      if (c >= N) continue;
      size_t idx = (size_t)r * N + c;
      if (EPI == 1) C[idx] += acc[i][j];
      else          C[idx] = acc[i][j];
    }
  }
}

// ------- depthwise causal conv3 + bias + silu, AND zg = silu(z) -------
__global__ void conv_kernel(const float* __restrict__ xz, const float* __restrict__ cw,
                            const float* __restrict__ cb, float* __restrict__ xi,
                            float* __restrict__ zg) {
  int idx = blockIdx.x * blockDim.x + threadIdx.x;
  if (idx >= NB * LSEQ * DI) return;
  int c = idx % DI;
  int bt = idx / DI;
  int t = bt % LSEQ, b = bt / LSEQ;
  const float* src = xz + (size_t)b * LSEQ * DXZ + c;
  float s = cb[c];
  float w0 = cw[c * 3 + 0], w1 = cw[c * 3 + 1], w2 = cw[c * 3 + 2];
  if (t >= 2) s = fmaf(w0, src[(size_t)(t - 2) * DXZ], s);
  if (t >= 1) s = fmaf(w1, src[(size_t)(t - 1) * DXZ], s);
  s = fmaf(w2, src[(size_t)t * DXZ], s);
  float sig = 1.f / (1.f + __expf(-s));
  xi[idx] = s * sig;
  float zv = src[(size_t)t * DXZ + DI];
  float zsig = 1.f / (1.f + __expf(-zv));
  zg[idx] = zv * zsig;
}

// ---------------- dt = softplus(dt_r @ dtwT + dtb) ----------------
__global__ __launch_bounds__(384)
void dt_kernel(const float* __restrict__ dbl, const float* __restrict__ dtwT,
               const float* __restrict__ dtb, float* __restrict__ dtout) {
  int row = blockIdx.x;
  int d = threadIdx.x;
  __shared__ float rr[DTR];
  if (d < DTR) rr[d] = dbl[(size_t)row * DBLW + d];
  __syncthreads();
  float s = dtb[d];
#pragma unroll
  for (int r = 0; r < DTR; ++r) s = fmaf(rr[r], dtwT[r * DI + d], s);
  float sp = fmaxf(s, 0.f) + log1pf(__expf(-fabsf(s)));
  dtout[(size_t)row * DI + d] = sp;
}

// ======== chunked selective scan, lane = channel, states in registers ========
// summaries: cumdt[bg][c][lane], hendT[((bg*NCH1+c)*NST+n)*64+lane],
//            hinitT[((bg*NCH+c)*NST+n)*64+lane]   with bg = b*NDG+dgrp

__global__ __launch_bounds__(256)
void scan_pass1(const float* __restrict__ dtp_, const float* __restrict__ xi,
                const float* __restrict__ dbl, const float* __restrict__ Alog,
                float* __restrict__ cumdt, float* __restrict__ hendT) {
  int gw = (blockIdx.x * blockDim.x + threadIdx.x) >> 6;  // wave id over NB*NDG*NCH1
  int lane = threadIdx.x & 63;
  int c = gw % NCH1;
  int bg = gw / NCH1;
  int b = bg / NDG, dgrp = bg % NDG;
  int d = dgrp * 64 + lane;
  int t0 = c * CS;

  float al2[NST];
  {
    const float4* Ap = (const float4*)(Alog + (size_t)d * NST);
#pragma unroll
    for (int j = 0; j < 16; ++j) {
      float4 v = Ap[j];
      al2[4 * j + 0] = -__expf(v.x) * LOG2E;
      al2[4 * j + 1] = -__expf(v.y) * LOG2E;
      al2[4 * j + 2] = -__expf(v.z) * LOG2E;
      al2[4 * j + 3] = -__expf(v.w) * LOG2E;
    }
  }
  float h[NST];
#pragma unroll
  for (int n = 0; n < NST; ++n) h[n] = 0.f;

  const float* dtp = dtp_ + ((size_t)b * LSEQ + t0) * DI + d;
  const float* up  = xi   + ((size_t)b * LSEQ + t0) * DI + d;
  const float* Bp  = dbl  + ((size_t)b * LSEQ + t0) * DBLW + DTR + lane;  // lane as n
  float cum = 0.f;
  float dtv = *dtp, uv = *up, Bv = *Bp;
  for (int t = 0; t < CS; ++t) {
    float n_dt = 0.f, n_u = 0.f, n_B = 0.f;
    if (t + 1 < CS) {
      dtp += DI; up += DI; Bp += DBLW;
      n_dt = *dtp; n_u = *up; n_B = *Bp;
    }
    float dtu = dtv * uv;
#pragma unroll
    for (int n = 0; n < NST; ++n) {
      float Bn = rdlane(Bv, n);
      float dA = exp2f(dtv * al2[n]);
      h[n] = fmaf(dA, h[n], dtu * Bn);
    }
    cum += dtv;
    dtv = n_dt; uv = n_u; Bv = n_B;
  }
  cumdt[(size_t)bg * NCH1 * 64 + (size_t)c * 64 + lane] = cum;
  float* hp = hendT + ((size_t)bg * NCH1 + c) * NST * 64 + lane;
#pragma unroll
  for (int n = 0; n < NST; ++n) hp[n * 64] = h[n];
}

// pass2: combine chunk summaries. block 256 = 4 waves; block -> (b,dgrp); wave w -> 16 n's
__global__ __launch_bounds__(256)
void scan_pass2(const float* __restrict__ cumdt, const float* __restrict__ hendT,
                const float* __restrict__ Alog, float* __restrict__ hinitT) {
  int bg = blockIdx.x;
  int lane = threadIdx.x & 63;
  int w = threadIdx.x >> 6;
  int n0 = w * 16;
  int dgrp = bg % NDG;
  int d = dgrp * 64 + lane;

  float al2[16];
#pragma unroll
  for (int j = 0; j < 16; ++j) al2[j] = -__expf(Alog[(size_t)d * NST + n0 + j]) * LOG2E;

  float h[16];
#pragma unroll
  for (int j = 0; j < 16; ++j) h[j] = 0.f;

  for (int c = 0; c < NCH; ++c) {
    float* hi = hinitT + ((size_t)bg * NCH + c) * NST * 64 + (size_t)n0 * 64 + lane;
#pragma unroll
    for (int j = 0; j < 16; ++j) hi[j * 64] = h[j];
    if (c < NCH1) {
      float cum = cumdt[(size_t)bg * NCH1 * 64 + (size_t)c * 64 + lane];
      const float* he = hendT + ((size_t)bg * NCH1 + c) * NST * 64 + (size_t)n0 * 64 + lane;
#pragma unroll
      for (int j = 0; j < 16; ++j) {
        float ap = exp2f(al2[j] * cum);
        h[j] = fmaf(ap, h[j], he[j * 64]);
      }
    }
  }
}

// pass3: full scan from hinit, y = (C.h + u*D)*zg
__global__ __launch_bounds__(256)
void scan_pass3(const float* __restrict__ dtp_, const float* __restrict__ xi,
                const float* __restrict__ zg, const float* __restrict__ dbl,
                const float* __restrict__ Alog, const float* __restrict__ Dpar,
                const float* __restrict__ hinitT, float* __restrict__ yg) {
  int gw = (blockIdx.x * blockDim.x + threadIdx.x) >> 6;  // over NB*NDG*NCH
  int lane = threadIdx.x & 63;
  int c = gw & (NCH - 1);
  int bg = gw >> 5;
  int b = bg / NDG, dgrp = bg % NDG;
  int d = dgrp * 64 + lane;
  int t0 = c * CS;
  int nsteps = (c == NCH - 1) ? (LSEQ - t0) : CS;

  float al2[NST];
  {
    const float4* Ap = (const float4*)(Alog + (size_t)d * NST);
#pragma unroll
    for (int j = 0; j < 16; ++j) {
      float4 v = Ap[j];
      al2[4 * j + 0] = -__expf(v.x) * LOG2E;
      al2[4 * j + 1] = -__expf(v.y) * LOG2E;
      al2[4 * j + 2] = -__expf(v.z) * LOG2E;
      al2[4 * j + 3] = -__expf(v.w) * LOG2E;
    }
  }
  float Dp = Dpar[d];
  float h[NST];
  {
    const float* hi = hinitT + ((size_t)bg * NCH + c) * NST * 64 + lane;
#pragma unroll
    for (int n = 0; n < NST; ++n) h[n] = hi[n * 64];
  }

  const float* dtp = dtp_ + ((size_t)b * LSEQ + t0) * DI + d;
  const float* up  = xi   + ((size_t)b * LSEQ + t0) * DI + d;
  const float* gp  = zg   + ((size_t)b * LSEQ + t0) * DI + d;
  const float* Bp  = dbl  + ((size_t)b * LSEQ + t0) * DBLW + DTR + lane;
  const float* Cp  = dbl  + ((size_t)b * LSEQ + t0) * DBLW + DTR + NST + lane;
  float* yp = yg + ((size_t)b * LSEQ + t0) * DI + d;

  float dtv = *dtp, uv = *up, gv = *gp, Bv = *Bp, Cv = *Cp;
  for (int t = 0; t < nsteps; ++t) {
    float n_dt = 0.f, n_u = 0.f, n_g = 0.f, n_B = 0.f, n_C = 0.f;
    if (t + 1 < nsteps) {
      dtp += DI; up += DI; gp += DI; Bp += DBLW; Cp += DBLW;
      n_dt = *dtp; n_u = *up; n_g = *gp; n_B = *Bp; n_C = *Cp;
    }
    float dtu = dtv * uv;
    float y = 0.f;
#pragma unroll
    for (int n = 0; n < NST; ++n) {
      float Bn = rdlane(Bv, n);
      float Cn = rdlane(Cv, n);
      float dA = exp2f(dtv * al2[n]);
      h[n] = fmaf(dA, h[n], dtu * Bn);
      y = fmaf(h[n], Cn, y);
    }
    float outv = fmaf(uv, Dp, y) * gv;
    *yp = outv;
    yp += DI;
    dtv = n_dt; uv = n_u; gv = n_g; Bv = n_B; Cv = n_C;
  }
}

// ---------------- final norm + masked mean pool + head ------------
__global__ __launch_bounds__(192)
void pool1_kernel(const float* __restrict__ x, const int* __restrict__ mask,
                  const float* __restrict__ fw, float* __restrict__ partial) {
  int b = blockIdx.x >> 6;
  int chunk = blockIdx.x & 63;
  int d = threadIdx.x;
  __shared__ float red[3];
  float w = fw[d];
  float acc = 0.f;
  for (int tt = 0; tt < 16; ++tt) {
    int t = chunk * 16 + tt;
    float v = x[((size_t)b * LSEQ + t) * DM + d];
    float ss = waveReduceSum(v * v);
    if ((d & 63) == 0) red[d >> 6] = ss;
    __syncthreads();
    float ms = (red[0] + red[1] + red[2]) * (1.f / DM);
    float m = (float)mask[b * TSEQ + t];
    acc = fmaf(v * rsqrtf(ms + 1e-6f) * w, m, acc);
    __syncthreads();
  }
  partial[((size_t)b * 64 + chunk) * DM + d] = acc;
}

__global__ __launch_bounds__(192)
void pool2_kernel(const float* __restrict__ partial, const int* __restrict__ mask,
                  const float* __restrict__ hw, const float* __restrict__ hb,
                  float* __restrict__ out) {
  int b = blockIdx.x;
  int d = threadIdx.x;
  float s = 0.f;
  for (int c = 0; c < 64; ++c) s += partial[((size_t)b * 64 + c) * DM + d];
  float den = 0.f;
  for (int t = d; t < TSEQ; t += DM) den += (float)mask[b * TSEQ + t];
  den = waveReduceSum(den);
  __shared__ float dred[3];
  __shared__ float pooled[DM];
  if ((d & 63) == 0) dred[d >> 6] = den;
  __syncthreads();
  float denom = fmaxf(dred[0] + dred[1] + dred[2], 1.f);
  pooled[d] = s / denom;
  __syncthreads();
  if (d < 2) {
    float acc = hb[d];
    for (int k = 0; k < DM; ++k) acc = fmaf(pooled[k], hw[d * DM + k], acc);
    out[b * 2 + d] = acc;
  }
}

}  // namespace

extern "C" void kernel_launch(void* const* d_in, const int* in_sizes, int n_in,
                              void* d_out, int out_size, void* d_ws, size_t ws_size,
                              hipStream_t stream) {
  const int*   ids    = (const int*)d_in[0];
  const int*   mask   = (const int*)d_in[1];
  const float* embed  = (const float*)d_in[2];
  const float* cls    = (const float*)d_in[3];
  const float* norm_w = (const float*)d_in[4];
  const float* in_w   = (const float*)d_in[5];
  const float* conv_w = (const float*)d_in[6];
  const float* conv_b = (const float*)d_in[7];
  const float* xp_w   = (const float*)d_in[8];
  const float* dtw    = (const float*)d_in[9];
  const float* dtb    = (const float*)d_in[10];
  const float* Alog   = (const float*)d_in[11];
  const float* Dpar   = (const float*)d_in[12];
  const float* ow     = (const float*)d_in[13];
  const float* fnw    = (const float*)d_in[14];
  const float* hw     = (const float*)d_in[15];
  const float* hb     = (const float*)d_in[16];
  float* out = (float*)d_out;

  float* ws = (float*)d_ws;
  size_t off = 0;
  float* x      = ws + off; off += (size_t)NB * LSEQ * DM;
  float* h      = ws + off; off += (size_t)NB * LSEQ * DM;
  float* xz     = ws + off; off += (size_t)NB * LSEQ * DXZ;
  float* xi     = ws + off; off += (size_t)NB * LSEQ * DI;
  float* zgbuf  = ws + off; off += (size_t)NB * LSEQ * DI;
  float* dblb   = ws + off; off += (size_t)NB * LSEQ * DBLW;
  float* dtbuf  = ws + off; off += (size_t)NB * LSEQ * DI;
  float* yg     = ws + off; off += (size_t)NB * LSEQ * DI;
  float* wT_in  = ws + off; off += (size_t)8 * DM * DXZ;
  float* wT_xp  = ws + off; off += (size_t)8 * DI * DBLW;
  float* wT_dt  = ws + off; off += (size_t)8 * DTR * DI;
  float* wT_ow  = ws + off; off += (size_t)8 * DI * DM;
  float* partial = ws + off; off += (size_t)NB * 64 * DM;
  float* cumdt  = ws + off; off += (size_t)NB * NDG * NCH1 * 64;        // 95K
  float* hendT  = ws + off; off += (size_t)NB * NDG * NCH1 * NST * 64;  // 6.09M
  float* hinitT = ws + off; off += (size_t)NB * NDG * NCH * NST * 64;   // 6.29M

  dim3 tb(32, 8);
  transpose_batched<<<dim3(6, 24, 8), tb, 0, stream>>>(in_w, wT_in, DXZ, DM);
  transpose_batched<<<dim3(12, 5, 8), tb, 0, stream>>>(xp_w, wT_xp, DBLW, DI);
  transpose_batched<<<dim3(1, 12, 8), tb, 0, stream>>>(dtw, wT_dt, DI, DTR);
  transpose_batched<<<dim3(12, 6, 8), tb, 0, stream>>>(ow, wT_ow, DM, DI);

  embed_kernel<<<(NB * LSEQ * DM) / 256, 256, 0, stream>>>(ids, embed, cls, x);

  for (int l = 0; l < 8; ++l) {
    rmsnorm_kernel<<<MROWS, 192, 0, stream>>>(x, norm_w + l * DM, h);
    gemm_kernel<0><<<dim3(DXZ / 64, (MROWS + 63) / 64), 256, 0, stream>>>(
        h, wT_in + (size_t)l * DM * DXZ, xz, MROWS, DXZ, DM);
    conv_kernel<<<(NB * LSEQ * DI) / 256, 256, 0, stream>>>(
        xz, conv_w + l * DI * 3, conv_b + l * DI, xi, zgbuf);
    gemm_kernel<0><<<dim3((DBLW + 63) / 64, (MROWS + 63) / 64), 256, 0, stream>>>(
        xi, wT_xp + (size_t)l * DI * DBLW, dblb, MROWS, DBLW, DI);
    dt_kernel<<<MROWS, DI, 0, stream>>>(dblb, wT_dt + l * DTR * DI, dtb + l * DI, dtbuf);
    // chunked scan (lane = channel, 64 states in registers)
    scan_pass1<<<(NB * NDG * NCH1 * 64) / 256, 256, 0, stream>>>(
        dtbuf, xi, dblb, Alog + (size_t)l * DI * NST, cumdt, hendT);
    scan_pass2<<<NB * NDG, 256, 0, stream>>>(
        cumdt, hendT, Alog + (size_t)l * DI * NST, hinitT);
    scan_pass3<<<(NB * NDG * NCH * 64) / 256, 256, 0, stream>>>(
        dtbuf, xi, zgbuf, dblb, Alog + (size_t)l * DI * NST, Dpar + l * DI, hinitT, yg);
    gemm_kernel<1><<<dim3(DM / 64, (MROWS + 63) / 64), 256, 0, stream>>>(
        yg, wT_ow + (size_t)l * DI * DM, x, MROWS, DM, DI);
  }

  pool1_kernel<<<NB * 64, 192, 0, stream>>>(x, mask, fnw, partial);
  pool2_kernel<<<NB, 192, 0, stream>>>(partial, mask, hw, hb, out);
}

// Round 4
// 2394.972 us; speedup vs baseline: 1.9976x; 1.1687x over previous
//
#include <hip/hip_runtime.h>
#include <hip/hip_bf16.h>
#include <cstddef>

namespace {

constexpr int NB   = 8;     // batch
constexpr int LSEQ = 1025;  // tokens incl. CLS
constexpr int TSEQ = 1024;
constexpr int DM   = 192;   // d_model
constexpr int DI   = 384;   // d_inner
constexpr int DXZ  = 768;   // 2*d_inner
constexpr int DBLW = 140;   // dt_rank + 2*d_state
constexpr int DTR  = 12;    // dt_rank
constexpr int NST  = 64;    // d_state
constexpr int MROWS = NB * LSEQ;  // 8200
constexpr int NCH  = 32;    // scan chunks
constexpr int CS   = 32;    // chunk size (last chunk = 33)
constexpr int NCH1 = NCH - 1;
constexpr int NDG  = DI / 64;  // 6 channel groups
constexpr int HST  = 32;    // states per wave (half of 64)
constexpr float LOG2E = 1.4426950408889634f;

__device__ __forceinline__ float waveReduceSum(float v) {
#pragma unroll
  for (int o = 32; o; o >>= 1) v += __shfl_xor(v, o, 64);
  return v;
}

__device__ __forceinline__ float rdlane(float v, int n) {
  return __int_as_float(__builtin_amdgcn_readlane(__float_as_int(v), n));
}

// ---------------- embed ----------------
__global__ void embed_kernel(const int* __restrict__ ids, const float* __restrict__ emb,
                             const float* __restrict__ cls, float* __restrict__ x) {
  int idx = blockIdx.x * blockDim.x + threadIdx.x;   // over NB*LSEQ*DM
  if (idx >= NB * LSEQ * DM) return;
  int d = idx % DM;
  int bt = idx / DM;
  int t = bt % LSEQ, b = bt / LSEQ;
  float v;
  if (t < TSEQ) v = emb[(size_t)ids[b * TSEQ + t] * DM + d];
  else          v = cls[d];
  x[idx] = v;
}

// ---------------- batched transpose ----------------
__global__ void transpose_batched(const float* __restrict__ in, float* __restrict__ out,
                                  int rows, int cols) {
  __shared__ float tile[32][33];
  int l = blockIdx.z;
  int r0 = blockIdx.y * 32, c0 = blockIdx.x * 32;
  const float* src = in + (size_t)l * rows * cols;
  float* dst = out + (size_t)l * rows * cols;
  int tx = threadIdx.x, ty = threadIdx.y;  // 32 x 8
#pragma unroll
  for (int i = 0; i < 32; i += 8) {
    int r = r0 + ty + i, c = c0 + tx;
    if (r < rows && c < cols) tile[ty + i][tx] = src[(size_t)r * cols + c];
  }
  __syncthreads();
#pragma unroll
  for (int i = 0; i < 32; i += 8) {
    int c = c0 + ty + i, r = r0 + tx;
    if (c < cols && r < rows) dst[(size_t)c * rows + r] = tile[tx][ty + i];
  }
}

// ---------------- rmsnorm ----------------
__global__ __launch_bounds__(192)
void rmsnorm_kernel(const float* __restrict__ x, const float* __restrict__ w,
                    float* __restrict__ h) {
  int row = blockIdx.x;
  int d = threadIdx.x;
  float v = x[(size_t)row * DM + d];
  float ss = waveReduceSum(v * v);
  __shared__ float red[3];
  if ((d & 63) == 0) red[d >> 6] = ss;
  __syncthreads();
  float ms = (red[0] + red[1] + red[2]) * (1.f / DM);
  h[(size_t)row * DM + d] = v * rsqrtf(ms + 1e-6f) * w[d];
}

// ---------------- generic fp32 GEMM; SUM2: A := A + A2 elementwise ----------------
template <int EPI, bool SUM2>
__global__ __launch_bounds__(256)
void gemm_kernel(const float* __restrict__ A, const float* __restrict__ A2,
                 const float* __restrict__ B, float* C, int M, int N, int K) {
  __shared__ __align__(16) float As[32][68];
  __shared__ __align__(16) float Bs[32][68];
  const int tid = threadIdx.x;
  const int row0 = blockIdx.y * 64;
  const int col0 = blockIdx.x * 64;
  const int tm = (tid >> 4) * 4;
  const int tn = (tid & 15) * 4;
  float acc[4][4] = {};
  for (int k0 = 0; k0 < K; k0 += 32) {
    {
      const int m = tid >> 2;
      const int kk = (tid & 3) * 8;
      float4 v0 = make_float4(0, 0, 0, 0), v1 = v0;
      if (row0 + m < M) {
        const float* src = A + (size_t)(row0 + m) * K + k0 + kk;
        v0 = *(const float4*)src;
        v1 = *(const float4*)(src + 4);
        if (SUM2) {
          const float* src2 = A2 + (size_t)(row0 + m) * K + k0 + kk;
          float4 w0 = *(const float4*)src2;
          float4 w1 = *(const float4*)(src2 + 4);
          v0.x += w0.x; v0.y += w0.y; v0.z += w0.z; v0.w += w0.w;
          v1.x += w1.x; v1.y += w1.y; v1.z += w1.z; v1.w += w1.w;
        }
      }
      As[kk + 0][m] = v0.x; As[kk + 1][m] = v0.y; As[kk + 2][m] = v0.z; As[kk + 3][m] = v0.w;
      As[kk + 4][m] = v1.x; As[kk + 5][m] = v1.y; As[kk + 6][m] = v1.z; As[kk + 7][m] = v1.w;
    }
    {
      const int kk = tid >> 3;
      const int n = (tid & 7) * 8;
      const float* src = B + (size_t)(k0 + kk) * N + col0 + n;
      float v[8];
      if (col0 + n + 8 <= N) {
        float4 v0 = *(const float4*)src;
        float4 v1 = *(const float4*)(src + 4);
        v[0] = v0.x; v[1] = v0.y; v[2] = v0.z; v[3] = v0.w;
        v[4] = v1.x; v[5] = v1.y; v[6] = v1.z; v[7] = v1.w;
      } else {
#pragma unroll
        for (int i = 0; i < 8; ++i) v[i] = (col0 + n + i < N) ? src[i] : 0.f;
      }
#pragma unroll
      for (int i = 0; i < 8; ++i) Bs[kk][n + i] = v[i];
    }
    __syncthreads();
#pragma unroll
    for (int kk = 0; kk < 32; ++kk) {
      float4 av = *(const float4*)&As[kk][tm];
      float4 bv = *(const float4*)&Bs[kk][tn];
      float a[4] = {av.x, av.y, av.z, av.w};
      float b[4] = {bv.x, bv.y, bv.z, bv.w};
#pragma unroll
      for (int i = 0; i < 4; ++i)
#pragma unroll
        for (int j = 0; j < 4; ++j) acc[i][j] = fmaf(a[i], b[j], acc[i][j]);
    }
    __syncthreads();
  }
#pragma unroll
  for (int i = 0; i < 4; ++i) {
    int r = row0 + tm + i;
    if (r >= M) continue;
#pragma unroll
    for (int j = 0; j < 4; ++j) {
      int c = col0 + tn + j;
      if (c >= N) continue;
      size_t idx = (size_t)r * N + c;
      if (EPI == 1) C[idx] += acc[i][j];
      else          C[idx] = acc[i][j];
    }
  }
}

// ------- depthwise causal conv3 + bias + silu, AND zg = silu(z) -------
__global__ void conv_kernel(const float* __restrict__ xz, const float* __restrict__ cw,
                            const float* __restrict__ cb, float* __restrict__ xi,
                            float* __restrict__ zg) {
  int idx = blockIdx.x * blockDim.x + threadIdx.x;
  if (idx >= NB * LSEQ * DI) return;
  int c = idx % DI;
  int bt = idx / DI;
  int t = bt % LSEQ, b = bt / LSEQ;
  const float* src = xz + (size_t)b * LSEQ * DXZ + c;
  float s = cb[c];
  float w0 = cw[c * 3 + 0], w1 = cw[c * 3 + 1], w2 = cw[c * 3 + 2];
  if (t >= 2) s = fmaf(w0, src[(size_t)(t - 2) * DXZ], s);
  if (t >= 1) s = fmaf(w1, src[(size_t)(t - 1) * DXZ], s);
  s = fmaf(w2, src[(size_t)t * DXZ], s);
  float sig = 1.f / (1.f + __expf(-s));
  xi[idx] = s * sig;
  float zv = src[(size_t)t * DXZ + DI];
  float zsig = 1.f / (1.f + __expf(-zv));
  zg[idx] = zv * zsig;
}

// ---------------- dt = softplus(dt_r @ dtwT + dtb) ----------------
__global__ __launch_bounds__(384)
void dt_kernel(const float* __restrict__ dbl, const float* __restrict__ dtwT,
               const float* __restrict__ dtb, float* __restrict__ dtout) {
  int row = blockIdx.x;
  int d = threadIdx.x;
  __shared__ float rr[DTR];
  if (d < DTR) rr[d] = dbl[(size_t)row * DBLW + d];
  __syncthreads();
  float s = dtb[d];
#pragma unroll
  for (int r = 0; r < DTR; ++r) s = fmaf(rr[r], dtwT[r * DI + d], s);
  float sp = fmaxf(s, 0.f) + log1pf(__expf(-fabsf(s)));
  dtout[(size_t)row * DI + d] = sp;
}

// ======== chunked selective scan, lane = channel, 32 states per wave ========
// summaries: cumdt[bg][c][lane], hendT[((bg*NCH1+c)*NST+n)*64+lane],
//            hinitT[((bg*NCH+c)*NST+n)*64+lane]   with bg = b*NDG+dgrp

__global__ __launch_bounds__(256)
void scan_pass1(const float* __restrict__ dtp_, const float* __restrict__ xi,
                const float* __restrict__ dbl, const float* __restrict__ Alog,
                float* __restrict__ cumdt, float* __restrict__ hendT) {
  int gw = (blockIdx.x * blockDim.x + threadIdx.x) >> 6;  // over NB*NDG*NCH1*2
  int lane = threadIdx.x & 63;
  int c2 = gw % (NCH1 * 2);
  int c = c2 >> 1;
  int half = c2 & 1;
  int bg = gw / (NCH1 * 2);
  int b = bg / NDG, dgrp = bg % NDG;
  int d = dgrp * 64 + lane;
  int n0 = half * HST;
  int t0 = c * CS;

  float al2[HST];
  {
    const float4* Ap = (const float4*)(Alog + (size_t)d * NST + n0);
#pragma unroll
    for (int j = 0; j < HST / 4; ++j) {
      float4 v = Ap[j];
      al2[4 * j + 0] = -__expf(v.x) * LOG2E;
      al2[4 * j + 1] = -__expf(v.y) * LOG2E;
      al2[4 * j + 2] = -__expf(v.z) * LOG2E;
      al2[4 * j + 3] = -__expf(v.w) * LOG2E;
    }
  }
  float h[HST];
#pragma unroll
  for (int j = 0; j < HST; ++j) h[j] = 0.f;

  const float* dtp = dtp_ + ((size_t)b * LSEQ + t0) * DI + d;
  const float* up  = xi   + ((size_t)b * LSEQ + t0) * DI + d;
  // B for this half: lanes 0-31 and 32-63 load identical 128B (broadcast fetch)
  const float* Bp  = dbl  + ((size_t)b * LSEQ + t0) * DBLW + DTR + n0 + (lane & 31);
  float cum = 0.f;
  float dtv = *dtp, uv = *up, Bv = *Bp;
  for (int t = 0; t < CS; ++t) {
    float n_dt = 0.f, n_u = 0.f, n_B = 0.f;
    if (t + 1 < CS) {
      dtp += DI; up += DI; Bp += DBLW;
      n_dt = *dtp; n_u = *up; n_B = *Bp;
    }
    float dtu = dtv * uv;
#pragma unroll
    for (int j = 0; j < HST; ++j) {
      float Bn = rdlane(Bv, j);           // const lane index
      float dA = exp2f(dtv * al2[j]);
      h[j] = fmaf(dA, h[j], dtu * Bn);
    }
    cum += dtv;
    dtv = n_dt; uv = n_u; Bv = n_B;
  }
  if (half == 0)
    cumdt[(size_t)bg * NCH1 * 64 + (size_t)c * 64 + lane] = cum;
  float* hp = hendT + ((size_t)bg * NCH1 + c) * NST * 64 + (size_t)n0 * 64 + lane;
#pragma unroll
  for (int j = 0; j < HST; ++j) hp[j * 64] = h[j];
}

// pass2: combine chunk summaries. block 256 = 4 waves; block -> bg; wave w -> 16 n's
__global__ __launch_bounds__(256)
void scan_pass2(const float* __restrict__ cumdt, const float* __restrict__ hendT,
                const float* __restrict__ Alog, float* __restrict__ hinitT) {
  int bg = blockIdx.x;
  int lane = threadIdx.x & 63;
  int w = threadIdx.x >> 6;
  int n0 = w * 16;
  int dgrp = bg % NDG;
  int d = dgrp * 64 + lane;

  float al2[16];
#pragma unroll
  for (int j = 0; j < 16; ++j) al2[j] = -__expf(Alog[(size_t)d * NST + n0 + j]) * LOG2E;

  float h[16];
#pragma unroll
  for (int j = 0; j < 16; ++j) h[j] = 0.f;

  for (int c = 0; c < NCH; ++c) {
    float* hi = hinitT + ((size_t)bg * NCH + c) * NST * 64 + (size_t)n0 * 64 + lane;
#pragma unroll
    for (int j = 0; j < 16; ++j) hi[j * 64] = h[j];
    if (c < NCH1) {
      float cum = cumdt[(size_t)bg * NCH1 * 64 + (size_t)c * 64 + lane];
      const float* he = hendT + ((size_t)bg * NCH1 + c) * NST * 64 + (size_t)n0 * 64 + lane;
#pragma unroll
      for (int j = 0; j < 16; ++j) {
        float ap = exp2f(al2[j] * cum);
        h[j] = fmaf(ap, h[j], he[j * 64]);
      }
    }
  }
}

// pass3: full scan from hinit; half0 writes (u*D + y0)*g to yg0, half1 writes y1*g to yg1
__global__ __launch_bounds__(256)
void scan_pass3(const float* __restrict__ dtp_, const float* __restrict__ xi,
                const float* __restrict__ zg, const float* __restrict__ dbl,
                const float* __restrict__ Alog, const float* __restrict__ Dpar,
                const float* __restrict__ hinitT, float* __restrict__ yg0,
                float* __restrict__ yg1) {
  int gw = (blockIdx.x * blockDim.x + threadIdx.x) >> 6;  // over NB*NDG*NCH*2
  int lane = threadIdx.x & 63;
  int half = gw & 1;
  int c = (gw >> 1) & (NCH - 1);
  int bg = gw >> 6;
  int b = bg / NDG, dgrp = bg % NDG;
  int d = dgrp * 64 + lane;
  int n0 = half * HST;
  int t0 = c * CS;
  int nsteps = (c == NCH - 1) ? (LSEQ - t0) : CS;

  float al2[HST];
  {
    const float4* Ap = (const float4*)(Alog + (size_t)d * NST + n0);
#pragma unroll
    for (int j = 0; j < HST / 4; ++j) {
      float4 v = Ap[j];
      al2[4 * j + 0] = -__expf(v.x) * LOG2E;
      al2[4 * j + 1] = -__expf(v.y) * LOG2E;
      al2[4 * j + 2] = -__expf(v.z) * LOG2E;
      al2[4 * j + 3] = -__expf(v.w) * LOG2E;
    }
  }
  float Dp = Dpar[d];
  float h[HST];
  {
    const float* hi = hinitT + ((size_t)bg * NCH + c) * NST * 64 + (size_t)n0 * 64 + lane;
#pragma unroll
    for (int j = 0; j < HST; ++j) h[j] = hi[j * 64];
  }

  const float* dtp = dtp_ + ((size_t)b * LSEQ + t0) * DI + d;
  const float* up  = xi   + ((size_t)b * LSEQ + t0) * DI + d;
  const float* gp  = zg   + ((size_t)b * LSEQ + t0) * DI + d;
  const float* Bp  = dbl  + ((size_t)b * LSEQ + t0) * DBLW + DTR + n0 + (lane & 31);
  const float* Cp  = dbl  + ((size_t)b * LSEQ + t0) * DBLW + DTR + NST + n0 + (lane & 31);
  float* yp = (half == 0 ? yg0 : yg1) + ((size_t)b * LSEQ + t0) * DI + d;

  float dtv = *dtp, uv = *up, gv = *gp, Bv = *Bp, Cv = *Cp;
  for (int t = 0; t < nsteps; ++t) {
    float n_dt = 0.f, n_u = 0.f, n_g = 0.f, n_B = 0.f, n_C = 0.f;
    if (t + 1 < nsteps) {
      dtp += DI; up += DI; gp += DI; Bp += DBLW; Cp += DBLW;
      n_dt = *dtp; n_u = *up; n_g = *gp; n_B = *Bp; n_C = *Cp;
    }
    float dtu = dtv * uv;
    float y = 0.f;
#pragma unroll
    for (int j = 0; j < HST; ++j) {
      float Bn = rdlane(Bv, j);
      float Cn = rdlane(Cv, j);
      float dA = exp2f(dtv * al2[j]);
      h[j] = fmaf(dA, h[j], dtu * Bn);
      y = fmaf(h[j], Cn, y);
    }
    float outv = (half == 0) ? fmaf(uv, Dp, y) * gv : y * gv;
    *yp = outv;
    yp += DI;
    dtv = n_dt; uv = n_u; gv = n_g; Bv = n_B; Cv = n_C;
  }
}

// ---------------- final norm + masked mean pool + head ------------
__global__ __launch_bounds__(192)
void pool1_kernel(const float* __restrict__ x, const int* __restrict__ mask,
                  const float* __restrict__ fw, float* __restrict__ partial) {
  int b = blockIdx.x >> 6;
  int chunk = blockIdx.x & 63;
  int d = threadIdx.x;
  __shared__ float red[3];
  float w = fw[d];
  float acc = 0.f;
  for (int tt = 0; tt < 16; ++tt) {
    int t = chunk * 16 + tt;
    float v = x[((size_t)b * LSEQ + t) * DM + d];
    float ss = waveReduceSum(v * v);
    if ((d & 63) == 0) red[d >> 6] = ss;
    __syncthreads();
    float ms = (red[0] + red[1] + red[2]) * (1.f / DM);
    float m = (float)mask[b * TSEQ + t];
    acc = fmaf(v * rsqrtf(ms + 1e-6f) * w, m, acc);
    __syncthreads();
  }
  partial[((size_t)b * 64 + chunk) * DM + d] = acc;
}

__global__ __launch_bounds__(192)
void pool2_kernel(const float* __restrict__ partial, const int* __restrict__ mask,
                  const float* __restrict__ hw, const float* __restrict__ hb,
                  float* __restrict__ out) {
  int b = blockIdx.x;
  int d = threadIdx.x;
  float s = 0.f;
  for (int c = 0; c < 64; ++c) s += partial[((size_t)b * 64 + c) * DM + d];
  float den = 0.f;
  for (int t = d; t < TSEQ; t += DM) den += (float)mask[b * TSEQ + t];
  den = waveReduceSum(den);
  __shared__ float dred[3];
  __shared__ float pooled[DM];
  if ((d & 63) == 0) dred[d >> 6] = den;
  __syncthreads();
  float denom = fmaxf(dred[0] + dred[1] + dred[2], 1.f);
  pooled[d] = s / denom;
  __syncthreads();
  if (d < 2) {
    float acc = hb[d];
    for (int k = 0; k < DM; ++k) acc = fmaf(pooled[k], hw[d * DM + k], acc);
    out[b * 2 + d] = acc;
  }
}

}  // namespace

extern "C" void kernel_launch(void* const* d_in, const int* in_sizes, int n_in,
                              void* d_out, int out_size, void* d_ws, size_t ws_size,
                              hipStream_t stream) {
  const int*   ids    = (const int*)d_in[0];
  const int*   mask   = (const int*)d_in[1];
  const float* embed  = (const float*)d_in[2];
  const float* cls    = (const float*)d_in[3];
  const float* norm_w = (const float*)d_in[4];
  const float* in_w   = (const float*)d_in[5];
  const float* conv_w = (const float*)d_in[6];
  const float* conv_b = (const float*)d_in[7];
  const float* xp_w   = (const float*)d_in[8];
  const float* dtw    = (const float*)d_in[9];
  const float* dtb    = (const float*)d_in[10];
  const float* Alog   = (const float*)d_in[11];
  const float* Dpar   = (const float*)d_in[12];
  const float* ow     = (const float*)d_in[13];
  const float* fnw    = (const float*)d_in[14];
  const float* hw     = (const float*)d_in[15];
  const float* hb     = (const float*)d_in[16];
  float* out = (float*)d_out;

  float* ws = (float*)d_ws;
  size_t off = 0;
  float* x      = ws + off; off += (size_t)NB * LSEQ * DM;
  float* h      = ws + off; off += (size_t)NB * LSEQ * DM;
  float* xz     = ws + off; off += (size_t)NB * LSEQ * DXZ;
  float* xi     = ws + off; off += (size_t)NB * LSEQ * DI;
  float* zgbuf  = ws + off; off += (size_t)NB * LSEQ * DI;
  float* dblb   = ws + off; off += (size_t)NB * LSEQ * DBLW;
  float* dtbuf  = ws + off; off += (size_t)NB * LSEQ * DI;
  float* yg0    = ws + off; off += (size_t)NB * LSEQ * DI;
  float* yg1    = ws + off; off += (size_t)NB * LSEQ * DI;
  float* wT_in  = ws + off; off += (size_t)8 * DM * DXZ;
  float* wT_xp  = ws + off; off += (size_t)8 * DI * DBLW;
  float* wT_dt  = ws + off; off += (size_t)8 * DTR * DI;
  float* wT_ow  = ws + off; off += (size_t)8 * DI * DM;
  float* partial = ws + off; off += (size_t)NB * 64 * DM;
  float* cumdt  = ws + off; off += (size_t)NB * NDG * NCH1 * 64;
  float* hendT  = ws + off; off += (size_t)NB * NDG * NCH1 * NST * 64;  // 6.09M
  float* hinitT = ws + off; off += (size_t)NB * NDG * NCH * NST * 64;   // 6.29M

  dim3 tb(32, 8);
  transpose_batched<<<dim3(6, 24, 8), tb, 0, stream>>>(in_w, wT_in, DXZ, DM);
  transpose_batched<<<dim3(12, 5, 8), tb, 0, stream>>>(xp_w, wT_xp, DBLW, DI);
  transpose_batched<<<dim3(1, 12, 8), tb, 0, stream>>>(dtw, wT_dt, DI, DTR);
  transpose_batched<<<dim3(12, 6, 8), tb, 0, stream>>>(ow, wT_ow, DM, DI);

  embed_kernel<<<(NB * LSEQ * DM) / 256, 256, 0, stream>>>(ids, embed, cls, x);

  for (int l = 0; l < 8; ++l) {
    rmsnorm_kernel<<<MROWS, 192, 0, stream>>>(x, norm_w + l * DM, h);
    gemm_kernel<0, false><<<dim3(DXZ / 64, (MROWS + 63) / 64), 256, 0, stream>>>(
        h, nullptr, wT_in + (size_t)l * DM * DXZ, xz, MROWS, DXZ, DM);
    conv_kernel<<<(NB * LSEQ * DI) / 256, 256, 0, stream>>>(
        xz, conv_w + l * DI * 3, conv_b + l * DI, xi, zgbuf);
    gemm_kernel<0, false><<<dim3((DBLW + 63) / 64, (MROWS + 63) / 64), 256, 0, stream>>>(
        xi, nullptr, wT_xp + (size_t)l * DI * DBLW, dblb, MROWS, DBLW, DI);
    dt_kernel<<<MROWS, DI, 0, stream>>>(dblb, wT_dt + l * DTR * DI, dtb + l * DI, dtbuf);
    // chunked scan (lane = channel, 32 states per wave)
    scan_pass1<<<(NB * NDG * NCH1 * 2 * 64) / 256, 256, 0, stream>>>(
        dtbuf, xi, dblb, Alog + (size_t)l * DI * NST, cumdt, hendT);
    scan_pass2<<<NB * NDG, 256, 0, stream>>>(
        cumdt, hendT, Alog + (size_t)l * DI * NST, hinitT);
    scan_pass3<<<(NB * NDG * NCH * 2 * 64) / 256, 256, 0, stream>>>(
        dtbuf, xi, zgbuf, dblb, Alog + (size_t)l * DI * NST, Dpar + l * DI, hinitT,
        yg0, yg1);
    gemm_kernel<1, true><<<dim3(DM / 64, (MROWS + 63) / 64), 256, 0, stream>>>(
        yg0, yg1, wT_ow + (size_t)l * DI * DM, x, MROWS, DM, DI);
  }

  pool1_kernel<<<NB * 64, 192, 0, stream>>>(x, mask, fnw, partial);
  pool2_kernel<<<NB, 192, 0, stream>>>(partial, mask, hw, hb, out);
}

// Round 5
// 2009.994 us; speedup vs baseline: 2.3802x; 1.1915x over previous
//
#include <hip/hip_runtime.h>
#include <hip/hip_bf16.h>
#include <cstddef>

namespace {

constexpr int NB   = 8;     // batch
constexpr int LSEQ = 1025;  // tokens incl. CLS
constexpr int TSEQ = 1024;
constexpr int DM   = 192;   // d_model
constexpr int DI   = 384;   // d_inner
constexpr int DXZ  = 768;   // 2*d_inner
constexpr int DBLW = 140;   // dt_rank + 2*d_state
constexpr int DTR  = 12;    // dt_rank
constexpr int NST  = 64;    // d_state
constexpr int MROWS = NB * LSEQ;  // 8200
constexpr int NCH  = 32;    // scan chunks
constexpr int CS   = 32;    // chunk size (last chunk = 33)
constexpr int NCH1 = NCH - 1;
constexpr int NDG  = DI / 64;  // 6 channel groups
constexpr int HST  = 32;    // states per wave
constexpr int XPAD = 144;   // padded rows for xp weight (>=140, mult of 16)
constexpr float LOG2E = 1.4426950408889634f;

using bf16x8 = __attribute__((ext_vector_type(8))) short;
using f32x4  = __attribute__((ext_vector_type(4))) float;

__device__ __forceinline__ float waveReduceSum(float v) {
#pragma unroll
  for (int o = 32; o; o >>= 1) v += __shfl_xor(v, o, 64);
  return v;
}

__device__ __forceinline__ float rdlane(float v, int n) {
  return __int_as_float(__builtin_amdgcn_readlane(__float_as_int(v), n));
}

__device__ __forceinline__ unsigned short f2bf(float v) {
  __hip_bfloat16 b = __float2bfloat16(v);
  return *reinterpret_cast<unsigned short*>(&b);
}

// ---------------- embed ----------------
__global__ void embed_kernel(const int* __restrict__ ids, const float* __restrict__ emb,
                             const float* __restrict__ cls, float* __restrict__ x) {
  int idx = blockIdx.x * blockDim.x + threadIdx.x;
  if (idx >= NB * LSEQ * DM) return;
  int d = idx % DM;
  int bt = idx / DM;
  int t = bt % LSEQ, b = bt / LSEQ;
  float v;
  if (t < TSEQ) v = emb[(size_t)ids[b * TSEQ + t] * DM + d];
  else          v = cls[d];
  x[idx] = v;
}

// ---------------- weight conversion ----------------
__global__ void cvt_bf16_kernel(const float* __restrict__ src, unsigned short* __restrict__ dst,
                                int n) {
  int idx = blockIdx.x * blockDim.x + threadIdx.x;
  if (idx < n) dst[idx] = f2bf(src[idx]);
}

// xp_w [8][140][384] -> padded bf16 [8][144][384]
__global__ void pad_xp_kernel(const float* __restrict__ src, unsigned short* __restrict__ dst) {
  int idx = blockIdx.x * blockDim.x + threadIdx.x;  // over 8*144*384
  if (idx >= 8 * XPAD * DI) return;
  int k = idx % DI;
  int n = (idx / DI) % XPAD;
  int l = idx / (DI * XPAD);
  float v = (n < DBLW) ? src[((size_t)l * DBLW + n) * DI + k] : 0.f;
  dst[idx] = f2bf(v);
}

// ---------------- batched transpose (for dtw only) ----------------
__global__ void transpose_batched(const float* __restrict__ in, float* __restrict__ out,
                                  int rows, int cols) {
  __shared__ float tile[32][33];
  int l = blockIdx.z;
  int r0 = blockIdx.y * 32, c0 = blockIdx.x * 32;
  const float* src = in + (size_t)l * rows * cols;
  float* dst = out + (size_t)l * rows * cols;
  int tx = threadIdx.x, ty = threadIdx.y;
#pragma unroll
  for (int i = 0; i < 32; i += 8) {
    int r = r0 + ty + i, c = c0 + tx;
    if (r < rows && c < cols) tile[ty + i][tx] = src[(size_t)r * cols + c];
  }
  __syncthreads();
#pragma unroll
  for (int i = 0; i < 32; i += 8) {
    int c = c0 + ty + i, r = r0 + tx;
    if (c < cols && r < rows) dst[(size_t)c * rows + r] = tile[tx][ty + i];
  }
}

// ---------------- rmsnorm -> bf16 ----------------
__global__ __launch_bounds__(192)
void rmsnorm_kernel(const float* __restrict__ x, const float* __restrict__ w,
                    unsigned short* __restrict__ h) {
  int row = blockIdx.x;
  int d = threadIdx.x;
  float v = x[(size_t)row * DM + d];
  float ss = waveReduceSum(v * v);
  __shared__ float red[3];
  if ((d & 63) == 0) red[d >> 6] = ss;
  __syncthreads();
  float ms = (red[0] + red[1] + red[2]) * (1.f / DM);
  h[(size_t)row * DM + d] = f2bf(v * rsqrtf(ms + 1e-6f) * w[d]);
}

// ---------------- bf16 MFMA GEMM: C[M,*] (=|+=) A[M,K] @ W[N,K]^T ----------------
// A: bf16 [M][K], W: bf16 [Nw][K] (original torch layout), C: fp32, row stride ldc.
// Block 256 = 4 waves, tile 128(M) x 64(N), BK=32 (one mfma per K-step).
template <int EPI>
__global__ __launch_bounds__(256)
void gemm_mfma(const unsigned short* __restrict__ A, const unsigned short* __restrict__ W,
               float* __restrict__ C, int M, int Nw, int Nstore, int K, int ldc) {
  __shared__ unsigned short Alds[128][40];  // +8 pad: conflict-free b128 reads
  __shared__ unsigned short Wlds[64][40];
  const int tid = threadIdx.x;
  const int w = tid >> 6, lane = tid & 63;
  const int r16 = lane & 15, g = lane >> 4;
  const int row0 = blockIdx.y * 128, col0 = blockIdx.x * 64;

  f32x4 acc[2][4];
#pragma unroll
  for (int mi = 0; mi < 2; ++mi)
#pragma unroll
    for (int ni = 0; ni < 4; ++ni) acc[mi][ni] = (f32x4){0.f, 0.f, 0.f, 0.f};

  for (int k0 = 0; k0 < K; k0 += 32) {
    // stage A tile: 128 rows x 32 k = 512 chunks of 8 bf16; 2 chunks/thread
#pragma unroll
    for (int cc = 0; cc < 2; ++cc) {
      int c = tid + cc * 256;
      int r = c >> 2, q = c & 3;
      uint4 v = make_uint4(0, 0, 0, 0);
      int grow = row0 + r;
      if (grow < M) v = *(const uint4*)(A + (size_t)grow * K + k0 + q * 8);
      *(uint4*)&Alds[r][q * 8] = v;
    }
    // stage W tile: 64 rows x 32 k = 256 chunks; 1 chunk/thread
    {
      int r = tid >> 2, q = tid & 3;
      uint4 v = make_uint4(0, 0, 0, 0);
      int gn = col0 + r;
      if (gn < Nw) v = *(const uint4*)(W + (size_t)gn * K + k0 + q * 8);
      *(uint4*)&Wlds[r][q * 8] = v;
    }
    __syncthreads();
    bf16x8 a_f[2], b_f[4];
#pragma unroll
    for (int mi = 0; mi < 2; ++mi)
      a_f[mi] = *(const bf16x8*)&Alds[w * 32 + mi * 16 + r16][g * 8];
#pragma unroll
    for (int ni = 0; ni < 4; ++ni)
      b_f[ni] = *(const bf16x8*)&Wlds[ni * 16 + r16][g * 8];
#pragma unroll
    for (int mi = 0; mi < 2; ++mi)
#pragma unroll
      for (int ni = 0; ni < 4; ++ni)
        acc[mi][ni] = __builtin_amdgcn_mfma_f32_16x16x32_bf16(a_f[mi], b_f[ni],
                                                              acc[mi][ni], 0, 0, 0);
    __syncthreads();
  }
  // epilogue: D frag (16x16): col = lane&15, row = 4*(lane>>4)+reg
#pragma unroll
  for (int mi = 0; mi < 2; ++mi) {
#pragma unroll
    for (int reg = 0; reg < 4; ++reg) {
      int row = row0 + w * 32 + mi * 16 + g * 4 + reg;
      if (row >= M) continue;
#pragma unroll
      for (int ni = 0; ni < 4; ++ni) {
        int col = col0 + ni * 16 + r16;
        if (col >= Nstore) continue;
        size_t idx = (size_t)row * ldc + col;
        if (EPI) C[idx] += acc[mi][ni][reg];
        else     C[idx] = acc[mi][ni][reg];
      }
    }
  }
}

// ------- depthwise causal conv3 + bias + silu (fp32 + bf16 out), zg = silu(z) -------
__global__ void conv_kernel(const float* __restrict__ xz, const float* __restrict__ cw,
                            const float* __restrict__ cb, float* __restrict__ xi,
                            unsigned short* __restrict__ xi16, float* __restrict__ zg) {
  int idx = blockIdx.x * blockDim.x + threadIdx.x;
  if (idx >= NB * LSEQ * DI) return;
  int c = idx % DI;
  int bt = idx / DI;
  int t = bt % LSEQ, b = bt / LSEQ;
  const float* src = xz + (size_t)b * LSEQ * DXZ + c;
  float s = cb[c];
  float w0 = cw[c * 3 + 0], w1 = cw[c * 3 + 1], w2 = cw[c * 3 + 2];
  if (t >= 2) s = fmaf(w0, src[(size_t)(t - 2) * DXZ], s);
  if (t >= 1) s = fmaf(w1, src[(size_t)(t - 1) * DXZ], s);
  s = fmaf(w2, src[(size_t)t * DXZ], s);
  float sig = 1.f / (1.f + __expf(-s));
  float u = s * sig;
  xi[idx] = u;
  xi16[idx] = f2bf(u);
  float zv = src[(size_t)t * DXZ + DI];
  float zsig = 1.f / (1.f + __expf(-zv));
  zg[idx] = zv * zsig;
}

// ---------------- dt = softplus(dt_r @ dtwT + dtb) ----------------
__global__ __launch_bounds__(384)
void dt_kernel(const float* __restrict__ dbl, const float* __restrict__ dtwT,
               const float* __restrict__ dtb, float* __restrict__ dtout) {
  int row = blockIdx.x;
  int d = threadIdx.x;
  __shared__ float rr[DTR];
  if (d < DTR) rr[d] = dbl[(size_t)row * DBLW + d];
  __syncthreads();
  float s = dtb[d];
#pragma unroll
  for (int r = 0; r < DTR; ++r) s = fmaf(rr[r], dtwT[r * DI + d], s);
  float sp = fmaxf(s, 0.f) + log1pf(__expf(-fabsf(s)));
  dtout[(size_t)row * DI + d] = sp;
}

// ---------------- ysum: yb16 = bf16(yg0 + yg1) ----------------
__global__ void ysum_kernel(const float* __restrict__ yg0, const float* __restrict__ yg1,
                            unsigned short* __restrict__ yb) {
  int idx = blockIdx.x * blockDim.x + threadIdx.x;
  if (idx >= NB * LSEQ * DI) return;
  yb[idx] = f2bf(yg0[idx] + yg1[idx]);
}

// ======== chunked selective scan, lane = channel, 32 states per wave ========
__global__ __launch_bounds__(256)
void scan_pass1(const float* __restrict__ dtp_, const float* __restrict__ xi,
                const float* __restrict__ dbl, const float* __restrict__ Alog,
                float* __restrict__ cumdt, float* __restrict__ hendT) {
  int gw = (blockIdx.x * blockDim.x + threadIdx.x) >> 6;
  int lane = threadIdx.x & 63;
  int c2 = gw % (NCH1 * 2);
  int c = c2 >> 1;
  int half = c2 & 1;
  int bg = gw / (NCH1 * 2);
  int b = bg / NDG, dgrp = bg % NDG;
  int d = dgrp * 64 + lane;
  int n0 = half * HST;
  int t0 = c * CS;

  float al2[HST];
  {
    const float4* Ap = (const float4*)(Alog + (size_t)d * NST + n0);
#pragma unroll
    for (int j = 0; j < HST / 4; ++j) {
      float4 v = Ap[j];
      al2[4 * j + 0] = -__expf(v.x) * LOG2E;
      al2[4 * j + 1] = -__expf(v.y) * LOG2E;
      al2[4 * j + 2] = -__expf(v.z) * LOG2E;
      al2[4 * j + 3] = -__expf(v.w) * LOG2E;
    }
  }
  float h[HST];
#pragma unroll
  for (int j = 0; j < HST; ++j) h[j] = 0.f;

  const float* dtp = dtp_ + ((size_t)b * LSEQ + t0) * DI + d;
  const float* up  = xi   + ((size_t)b * LSEQ + t0) * DI + d;
  const float* Bp  = dbl  + ((size_t)b * LSEQ + t0) * DBLW + DTR + n0 + (lane & 31);
  float cum = 0.f;
  float dtv = *dtp, uv = *up, Bv = *Bp;
  for (int t = 0; t < CS; ++t) {
    float n_dt = 0.f, n_u = 0.f, n_B = 0.f;
    if (t + 1 < CS) {
      dtp += DI; up += DI; Bp += DBLW;
      n_dt = *dtp; n_u = *up; n_B = *Bp;
    }
    float dtu = dtv * uv;
#pragma unroll
    for (int j = 0; j < HST; ++j) {
      float Bn = rdlane(Bv, j);
      float dA = exp2f(dtv * al2[j]);
      h[j] = fmaf(dA, h[j], dtu * Bn);
    }
    cum += dtv;
    dtv = n_dt; uv = n_u; Bv = n_B;
  }
  if (half == 0)
    cumdt[(size_t)bg * NCH1 * 64 + (size_t)c * 64 + lane] = cum;
  float* hp = hendT + ((size_t)bg * NCH1 + c) * NST * 64 + (size_t)n0 * 64 + lane;
#pragma unroll
  for (int j = 0; j < HST; ++j) hp[j * 64] = h[j];
}

__global__ __launch_bounds__(256)
void scan_pass2(const float* __restrict__ cumdt, const float* __restrict__ hendT,
                const float* __restrict__ Alog, float* __restrict__ hinitT) {
  int bg = blockIdx.x;
  int lane = threadIdx.x & 63;
  int w = threadIdx.x >> 6;
  int n0 = w * 16;
  int dgrp = bg % NDG;
  int d = dgrp * 64 + lane;

  float al2[16];
#pragma unroll
  for (int j = 0; j < 16; ++j) al2[j] = -__expf(Alog[(size_t)d * NST + n0 + j]) * LOG2E;

  float h[16];
#pragma unroll
  for (int j = 0; j < 16; ++j) h[j] = 0.f;

  for (int c = 0; c < NCH; ++c) {
    float* hi = hinitT + ((size_t)bg * NCH + c) * NST * 64 + (size_t)n0 * 64 + lane;
#pragma unroll
    for (int j = 0; j < 16; ++j) hi[j * 64] = h[j];
    if (c < NCH1) {
      float cum = cumdt[(size_t)bg * NCH1 * 64 + (size_t)c * 64 + lane];
      const float* he = hendT + ((size_t)bg * NCH1 + c) * NST * 64 + (size_t)n0 * 64 + lane;
#pragma unroll
      for (int j = 0; j < 16; ++j) {
        float ap = exp2f(al2[j] * cum);
        h[j] = fmaf(ap, h[j], he[j * 64]);
      }
    }
  }
}

__global__ __launch_bounds__(256)
void scan_pass3(const float* __restrict__ dtp_, const float* __restrict__ xi,
                const float* __restrict__ zg, const float* __restrict__ dbl,
                const float* __restrict__ Alog, const float* __restrict__ Dpar,
                const float* __restrict__ hinitT, float* __restrict__ yg0,
                float* __restrict__ yg1) {
  int gw = (blockIdx.x * blockDim.x + threadIdx.x) >> 6;
  int lane = threadIdx.x & 63;
  int half = gw & 1;
  int c = (gw >> 1) & (NCH - 1);
  int bg = gw >> 6;
  int b = bg / NDG, dgrp = bg % NDG;
  int d = dgrp * 64 + lane;
  int n0 = half * HST;
  int t0 = c * CS;
  int nsteps = (c == NCH - 1) ? (LSEQ - t0) : CS;

  float al2[HST];
  {
    const float4* Ap = (const float4*)(Alog + (size_t)d * NST + n0);
#pragma unroll
    for (int j = 0; j < HST / 4; ++j) {
      float4 v = Ap[j];
      al2[4 * j + 0] = -__expf(v.x) * LOG2E;
      al2[4 * j + 1] = -__expf(v.y) * LOG2E;
      al2[4 * j + 2] = -__expf(v.z) * LOG2E;
      al2[4 * j + 3] = -__expf(v.w) * LOG2E;
    }
  }
  float Dp = Dpar[d];
  float h[HST];
  {
    const float* hi = hinitT + ((size_t)bg * NCH + c) * NST * 64 + (size_t)n0 * 64 + lane;
#pragma unroll
    for (int j = 0; j < HST; ++j) h[j] = hi[j * 64];
  }

  const float* dtp = dtp_ + ((size_t)b * LSEQ + t0) * DI + d;
  const float* up  = xi   + ((size_t)b * LSEQ + t0) * DI + d;
  const float* gp  = zg   + ((size_t)b * LSEQ + t0) * DI + d;
  const float* Bp  = dbl  + ((size_t)b * LSEQ + t0) * DBLW + DTR + n0 + (lane & 31);
  const float* Cp  = dbl  + ((size_t)b * LSEQ + t0) * DBLW + DTR + NST + n0 + (lane & 31);
  float* yp = (half == 0 ? yg0 : yg1) + ((size_t)b * LSEQ + t0) * DI + d;

  float dtv = *dtp, uv = *up, gv = *gp, Bv = *Bp, Cv = *Cp;
  for (int t = 0; t < nsteps; ++t) {
    float n_dt = 0.f, n_u = 0.f, n_g = 0.f, n_B = 0.f, n_C = 0.f;
    if (t + 1 < nsteps) {
      dtp += DI; up += DI; gp += DI; Bp += DBLW; Cp += DBLW;
      n_dt = *dtp; n_u = *up; n_g = *gp; n_B = *Bp; n_C = *Cp;
    }
    float dtu = dtv * uv;
    float y = 0.f;
#pragma unroll
    for (int j = 0; j < HST; ++j) {
      float Bn = rdlane(Bv, j);
      float Cn = rdlane(Cv, j);
      float dA = exp2f(dtv * al2[j]);
      h[j] = fmaf(dA, h[j], dtu * Bn);
      y = fmaf(h[j], Cn, y);
    }
    float outv = (half == 0) ? fmaf(uv, Dp, y) * gv : y * gv;
    *yp = outv;
    yp += DI;
    dtv = n_dt; uv = n_u; gv = n_g; Bv = n_B; Cv = n_C;
  }
}

// ---------------- final norm + masked mean pool + head ------------
__global__ __launch_bounds__(192)
void pool1_kernel(const float* __restrict__ x, const int* __restrict__ mask,
                  const float* __restrict__ fw, float* __restrict__ partial) {
  int b = blockIdx.x >> 6;
  int chunk = blockIdx.x & 63;
  int d = threadIdx.x;
  __shared__ float red[3];
  float w = fw[d];
  float acc = 0.f;
  for (int tt = 0; tt < 16; ++tt) {
    int t = chunk * 16 + tt;
    float v = x[((size_t)b * LSEQ + t) * DM + d];
    float ss = waveReduceSum(v * v);
    if ((d & 63) == 0) red[d >> 6] = ss;
    __syncthreads();
    float ms = (red[0] + red[1] + red[2]) * (1.f / DM);
    float m = (float)mask[b * TSEQ + t];
    acc = fmaf(v * rsqrtf(ms + 1e-6f) * w, m, acc);
    __syncthreads();
  }
  partial[((size_t)b * 64 + chunk) * DM + d] = acc;
}

__global__ __launch_bounds__(192)
void pool2_kernel(const float* __restrict__ partial, const int* __restrict__ mask,
                  const float* __restrict__ hw, const float* __restrict__ hb,
                  float* __restrict__ out) {
  int b = blockIdx.x;
  int d = threadIdx.x;
  float s = 0.f;
  for (int c = 0; c < 64; ++c) s += partial[((size_t)b * 64 + c) * DM + d];
  float den = 0.f;
  for (int t = d; t < TSEQ; t += DM) den += (float)mask[b * TSEQ + t];
  den = waveReduceSum(den);
  __shared__ float dred[3];
  __shared__ float pooled[DM];
  if ((d & 63) == 0) dred[d >> 6] = den;
  __syncthreads();
  float denom = fmaxf(dred[0] + dred[1] + dred[2], 1.f);
  pooled[d] = s / denom;
  __syncthreads();
  if (d < 2) {
    float acc = hb[d];
    for (int k = 0; k < DM; ++k) acc = fmaf(pooled[k], hw[d * DM + k], acc);
    out[b * 2 + d] = acc;
  }
}

}  // namespace

extern "C" void kernel_launch(void* const* d_in, const int* in_sizes, int n_in,
                              void* d_out, int out_size, void* d_ws, size_t ws_size,
                              hipStream_t stream) {
  const int*   ids    = (const int*)d_in[0];
  const int*   mask   = (const int*)d_in[1];
  const float* embed  = (const float*)d_in[2];
  const float* cls    = (const float*)d_in[3];
  const float* norm_w = (const float*)d_in[4];
  const float* in_w   = (const float*)d_in[5];
  const float* conv_w = (const float*)d_in[6];
  const float* conv_b = (const float*)d_in[7];
  const float* xp_w   = (const float*)d_in[8];
  const float* dtw    = (const float*)d_in[9];
  const float* dtb    = (const float*)d_in[10];
  const float* Alog   = (const float*)d_in[11];
  const float* Dpar   = (const float*)d_in[12];
  const float* ow     = (const float*)d_in[13];
  const float* fnw    = (const float*)d_in[14];
  const float* hw     = (const float*)d_in[15];
  const float* hb     = (const float*)d_in[16];
  float* out = (float*)d_out;

  // byte allocator over workspace (256B aligned)
  char* base = (char*)d_ws;
  size_t off = 0;
  auto alloc = [&](size_t bytes) -> void* {
    void* p = base + off;
    off = (off + bytes + 255) & ~(size_t)255;
    return p;
  };

  float* x      = (float*)alloc((size_t)NB * LSEQ * DM * 4);
  unsigned short* h16 = (unsigned short*)alloc((size_t)NB * LSEQ * DM * 2);
  float* xz     = (float*)alloc((size_t)NB * LSEQ * DXZ * 4);
  float* xi     = (float*)alloc((size_t)NB * LSEQ * DI * 4);
  unsigned short* xi16 = (unsigned short*)alloc((size_t)NB * LSEQ * DI * 2);
  float* zgbuf  = (float*)alloc((size_t)NB * LSEQ * DI * 4);
  float* dblb   = (float*)alloc((size_t)NB * LSEQ * DBLW * 4);
  float* dtbuf  = (float*)alloc((size_t)NB * LSEQ * DI * 4);
  float* yg0    = (float*)alloc((size_t)NB * LSEQ * DI * 4);
  float* yg1    = (float*)alloc((size_t)NB * LSEQ * DI * 4);
  unsigned short* yb16 = (unsigned short*)alloc((size_t)NB * LSEQ * DI * 2);
  unsigned short* wb_in = (unsigned short*)alloc((size_t)8 * DXZ * DM * 2);
  unsigned short* wb_xp = (unsigned short*)alloc((size_t)8 * XPAD * DI * 2);
  unsigned short* wb_ow = (unsigned short*)alloc((size_t)8 * DM * DI * 2);
  float* wT_dt  = (float*)alloc((size_t)8 * DTR * DI * 4);
  float* partial = (float*)alloc((size_t)NB * 64 * DM * 4);
  float* cumdt  = (float*)alloc((size_t)NB * NDG * NCH1 * 64 * 4);
  float* hendT  = (float*)alloc((size_t)NB * NDG * NCH1 * NST * 64 * 4);
  float* hinitT = (float*)alloc((size_t)NB * NDG * NCH * NST * 64 * 4);

  // one-time conversions (replayed each call; cheap)
  cvt_bf16_kernel<<<(8 * DXZ * DM + 255) / 256, 256, 0, stream>>>(in_w, wb_in, 8 * DXZ * DM);
  pad_xp_kernel<<<(8 * XPAD * DI + 255) / 256, 256, 0, stream>>>(xp_w, wb_xp);
  cvt_bf16_kernel<<<(8 * DM * DI + 255) / 256, 256, 0, stream>>>(ow, wb_ow, 8 * DM * DI);
  dim3 tb(32, 8);
  transpose_batched<<<dim3(1, 12, 8), tb, 0, stream>>>(dtw, wT_dt, DI, DTR);

  embed_kernel<<<(NB * LSEQ * DM) / 256, 256, 0, stream>>>(ids, embed, cls, x);

  const int mtiles = (MROWS + 127) / 128;  // 65
  for (int l = 0; l < 8; ++l) {
    rmsnorm_kernel<<<MROWS, 192, 0, stream>>>(x, norm_w + l * DM, h16);
    // xz = h @ in_w^T   (M=8200, N=768, K=192)
    gemm_mfma<0><<<dim3(DXZ / 64, mtiles), 256, 0, stream>>>(
        h16, wb_in + (size_t)l * DXZ * DM, xz, MROWS, DXZ, DXZ, DM, DXZ);
    conv_kernel<<<(NB * LSEQ * DI) / 256, 256, 0, stream>>>(
        xz, conv_w + l * DI * 3, conv_b + l * DI, xi, xi16, zgbuf);
    // dbl = xi @ xp_w^T  (M=8200, N=140(pad144), K=384)
    gemm_mfma<0><<<dim3(XPAD / 64 + 1, mtiles), 256, 0, stream>>>(
        xi16, wb_xp + (size_t)l * XPAD * DI, dblb, MROWS, XPAD, DBLW, DI, DBLW);
    dt_kernel<<<MROWS, DI, 0, stream>>>(dblb, wT_dt + l * DTR * DI, dtb + l * DI, dtbuf);
    // chunked scan
    scan_pass1<<<(NB * NDG * NCH1 * 2 * 64) / 256, 256, 0, stream>>>(
        dtbuf, xi, dblb, Alog + (size_t)l * DI * NST, cumdt, hendT);
    scan_pass2<<<NB * NDG, 256, 0, stream>>>(
        cumdt, hendT, Alog + (size_t)l * DI * NST, hinitT);
    scan_pass3<<<(NB * NDG * NCH * 2 * 64) / 256, 256, 0, stream>>>(
        dtbuf, xi, zgbuf, dblb, Alog + (size_t)l * DI * NST, Dpar + l * DI, hinitT,
        yg0, yg1);
    ysum_kernel<<<(NB * LSEQ * DI + 255) / 256, 256, 0, stream>>>(yg0, yg1, yb16);
    // x += y @ ow^T  (M=8200, N=192, K=384)
    gemm_mfma<1><<<dim3(DM / 64, mtiles), 256, 0, stream>>>(
        yb16, wb_ow + (size_t)l * DM * DI, x, MROWS, DM, DM, DI, DM);
  }

  pool1_kernel<<<NB * 64, 192, 0, stream>>>(x, mask, fnw, partial);
  pool2_kernel<<<NB, 192, 0, stream>>>(partial, mask, hw, hb, out);
}

// Round 6
// 1867.801 us; speedup vs baseline: 2.5614x; 1.0761x over previous
//
#include <hip/hip_runtime.h>
#include <hip/hip_bf16.h>
#include <cstddef>

namespace {

constexpr int NB   = 8;     // batch
constexpr int LSEQ = 1025;  // tokens incl. CLS
constexpr int TSEQ = 1024;
constexpr int DM   = 192;   // d_model
constexpr int DI   = 384;   // d_inner
constexpr int DXZ  = 768;   // 2*d_inner
constexpr int DBLW = 140;   // dt_rank + 2*d_state
constexpr int DTR  = 12;    // dt_rank
constexpr int NST  = 64;    // d_state
constexpr int MROWS = NB * LSEQ;  // 8200
constexpr int NCH  = 32;    // scan chunks
constexpr int CS   = 32;    // chunk size (last chunk = 33)
constexpr int NCH1 = NCH - 1;
constexpr int NDG  = DI / 64;  // 6 channel groups
constexpr int HST  = 32;    // states per wave
constexpr int XPAD = 144;   // padded rows for xp weight
constexpr float LOG2E = 1.4426950408889634f;

using bf16x8 = __attribute__((ext_vector_type(8))) short;
using f32x4  = __attribute__((ext_vector_type(4))) float;
using f32x2  = __attribute__((ext_vector_type(2))) float;

__device__ __forceinline__ float waveReduceSum(float v) {
#pragma unroll
  for (int o = 32; o; o >>= 1) v += __shfl_xor(v, o, 64);
  return v;
}

__device__ __forceinline__ unsigned short f2bf(float v) {
  __hip_bfloat16 b = __float2bfloat16(v);
  return *reinterpret_cast<unsigned short*>(&b);
}

// packed f32 math (v_pk_* = 2 FLOP-lanes per issue slot)
__device__ __forceinline__ f32x2 pk_mul(f32x2 a, f32x2 b) {
  f32x2 d;
  asm("v_pk_mul_f32 %0, %1, %2" : "=v"(d) : "v"(a), "v"(b));
  return d;
}
__device__ __forceinline__ f32x2 pk_fma(f32x2 a, f32x2 b, f32x2 c) {
  f32x2 d;
  asm("v_pk_fma_f32 %0, %1, %2, %3" : "=v"(d) : "v"(a), "v"(b), "v"(c));
  return d;
}

// ---------------- embed ----------------
__global__ void embed_kernel(const int* __restrict__ ids, const float* __restrict__ emb,
                             const float* __restrict__ cls, float* __restrict__ x) {
  int idx = blockIdx.x * blockDim.x + threadIdx.x;
  if (idx >= NB * LSEQ * DM) return;
  int d = idx % DM;
  int bt = idx / DM;
  int t = bt % LSEQ, b = bt / LSEQ;
  float v;
  if (t < TSEQ) v = emb[(size_t)ids[b * TSEQ + t] * DM + d];
  else          v = cls[d];
  x[idx] = v;
}

// ---------------- weight conversion ----------------
__global__ void cvt_bf16_kernel(const float* __restrict__ src, unsigned short* __restrict__ dst,
                                int n) {
  int idx = blockIdx.x * blockDim.x + threadIdx.x;
  if (idx < n) dst[idx] = f2bf(src[idx]);
}

// xp_w [8][140][384] -> padded bf16 [8][144][384]
__global__ void pad_xp_kernel(const float* __restrict__ src, unsigned short* __restrict__ dst) {
  int idx = blockIdx.x * blockDim.x + threadIdx.x;
  if (idx >= 8 * XPAD * DI) return;
  int k = idx % DI;
  int n = (idx / DI) % XPAD;
  int l = idx / (DI * XPAD);
  float v = (n < DBLW) ? src[((size_t)l * DBLW + n) * DI + k] : 0.f;
  dst[idx] = f2bf(v);
}

// ---------------- batched transpose (for dtw only) ----------------
__global__ void transpose_batched(const float* __restrict__ in, float* __restrict__ out,
                                  int rows, int cols) {
  __shared__ float tile[32][33];
  int l = blockIdx.z;
  int r0 = blockIdx.y * 32, c0 = blockIdx.x * 32;
  const float* src = in + (size_t)l * rows * cols;
  float* dst = out + (size_t)l * rows * cols;
  int tx = threadIdx.x, ty = threadIdx.y;
#pragma unroll
  for (int i = 0; i < 32; i += 8) {
    int r = r0 + ty + i, c = c0 + tx;
    if (r < rows && c < cols) tile[ty + i][tx] = src[(size_t)r * cols + c];
  }
  __syncthreads();
#pragma unroll
  for (int i = 0; i < 32; i += 8) {
    int c = c0 + ty + i, r = r0 + tx;
    if (c < cols && r < rows) dst[(size_t)c * rows + r] = tile[tx][ty + i];
  }
}

// ---------------- rmsnorm -> bf16 ----------------
__global__ __launch_bounds__(192)
void rmsnorm_kernel(const float* __restrict__ x, const float* __restrict__ w,
                    unsigned short* __restrict__ h) {
  int row = blockIdx.x;
  int d = threadIdx.x;
  float v = x[(size_t)row * DM + d];
  float ss = waveReduceSum(v * v);
  __shared__ float red[3];
  if ((d & 63) == 0) red[d >> 6] = ss;
  __syncthreads();
  float ms = (red[0] + red[1] + red[2]) * (1.f / DM);
  h[(size_t)row * DM + d] = f2bf(v * rsqrtf(ms + 1e-6f) * w[d]);
}

// ---------------- bf16 MFMA GEMM: C[M,*] (=|+=) A[M,K] @ W[N,K]^T ----------------
template <int EPI>
__global__ __launch_bounds__(256)
void gemm_mfma(const unsigned short* __restrict__ A, const unsigned short* __restrict__ W,
               float* __restrict__ C, int M, int Nw, int Nstore, int K, int ldc) {
  __shared__ unsigned short Alds[128][40];
  __shared__ unsigned short Wlds[64][40];
  const int tid = threadIdx.x;
  const int w = tid >> 6, lane = tid & 63;
  const int r16 = lane & 15, g = lane >> 4;
  const int row0 = blockIdx.y * 128, col0 = blockIdx.x * 64;

  f32x4 acc[2][4];
#pragma unroll
  for (int mi = 0; mi < 2; ++mi)
#pragma unroll
    for (int ni = 0; ni < 4; ++ni) acc[mi][ni] = (f32x4){0.f, 0.f, 0.f, 0.f};

  for (int k0 = 0; k0 < K; k0 += 32) {
#pragma unroll
    for (int cc = 0; cc < 2; ++cc) {
      int c = tid + cc * 256;
      int r = c >> 2, q = c & 3;
      uint4 v = make_uint4(0, 0, 0, 0);
      int grow = row0 + r;
      if (grow < M) v = *(const uint4*)(A + (size_t)grow * K + k0 + q * 8);
      *(uint4*)&Alds[r][q * 8] = v;
    }
    {
      int r = tid >> 2, q = tid & 3;
      uint4 v = make_uint4(0, 0, 0, 0);
      int gn = col0 + r;
      if (gn < Nw) v = *(const uint4*)(W + (size_t)gn * K + k0 + q * 8);
      *(uint4*)&Wlds[r][q * 8] = v;
    }
    __syncthreads();
    bf16x8 a_f[2], b_f[4];
#pragma unroll
    for (int mi = 0; mi < 2; ++mi)
      a_f[mi] = *(const bf16x8*)&Alds[w * 32 + mi * 16 + r16][g * 8];
#pragma unroll
    for (int ni = 0; ni < 4; ++ni)
      b_f[ni] = *(const bf16x8*)&Wlds[ni * 16 + r16][g * 8];
#pragma unroll
    for (int mi = 0; mi < 2; ++mi)
#pragma unroll
      for (int ni = 0; ni < 4; ++ni)
        acc[mi][ni] = __builtin_amdgcn_mfma_f32_16x16x32_bf16(a_f[mi], b_f[ni],
                                                              acc[mi][ni], 0, 0, 0);
    __syncthreads();
  }
#pragma unroll
  for (int mi = 0; mi < 2; ++mi) {
#pragma unroll
    for (int reg = 0; reg < 4; ++reg) {
      int row = row0 + w * 32 + mi * 16 + g * 4 + reg;
      if (row >= M) continue;
#pragma unroll
      for (int ni = 0; ni < 4; ++ni) {
        int col = col0 + ni * 16 + r16;
        if (col >= Nstore) continue;
        size_t idx = (size_t)row * ldc + col;
        if (EPI) C[idx] += acc[mi][ni][reg];
        else     C[idx] = acc[mi][ni][reg];
      }
    }
  }
}

// ------- depthwise causal conv3 + bias + silu (fp32 + bf16 out), zg = silu(z) -------
__global__ void conv_kernel(const float* __restrict__ xz, const float* __restrict__ cw,
                            const float* __restrict__ cb, float* __restrict__ xi,
                            unsigned short* __restrict__ xi16, float* __restrict__ zg) {
  int idx = blockIdx.x * blockDim.x + threadIdx.x;
  if (idx >= NB * LSEQ * DI) return;
  int c = idx % DI;
  int bt = idx / DI;
  int t = bt % LSEQ, b = bt / LSEQ;
  const float* src = xz + (size_t)b * LSEQ * DXZ + c;
  float s = cb[c];
  float w0 = cw[c * 3 + 0], w1 = cw[c * 3 + 1], w2 = cw[c * 3 + 2];
  if (t >= 2) s = fmaf(w0, src[(size_t)(t - 2) * DXZ], s);
  if (t >= 1) s = fmaf(w1, src[(size_t)(t - 1) * DXZ], s);
  s = fmaf(w2, src[(size_t)t * DXZ], s);
  float sig = 1.f / (1.f + __expf(-s));
  float u = s * sig;
  xi[idx] = u;
  xi16[idx] = f2bf(u);
  float zv = src[(size_t)t * DXZ + DI];
  float zsig = 1.f / (1.f + __expf(-zv));
  zg[idx] = zv * zsig;
}

// ---------------- dt = softplus(dt_r @ dtwT + dtb), 4 rows per block ----------------
__global__ __launch_bounds__(384)
void dt_kernel(const float* __restrict__ dbl, const float* __restrict__ dtwT,
               const float* __restrict__ dtb, float* __restrict__ dtout) {
  int row0 = blockIdx.x * 4;
  int d = threadIdx.x;
  __shared__ float rr[4][DTR];
  if (d < 4 * DTR) rr[d / DTR][d % DTR] = dbl[(size_t)(row0 + d / DTR) * DBLW + (d % DTR)];
  float w[DTR];
#pragma unroll
  for (int r = 0; r < DTR; ++r) w[r] = dtwT[r * DI + d];
  float bias = dtb[d];
  __syncthreads();
#pragma unroll
  for (int q = 0; q < 4; ++q) {
    float s = bias;
#pragma unroll
    for (int r = 0; r < DTR; ++r) s = fmaf(rr[q][r], w[r], s);
    float sp = fmaxf(s, 0.f) + log1pf(__expf(-fabsf(s)));
    dtout[(size_t)(row0 + q) * DI + d] = sp;
  }
}

// ---------------- ysum: yb16 = bf16(yg0 + yg1) ----------------
__global__ void ysum_kernel(const float* __restrict__ yg0, const float* __restrict__ yg1,
                            unsigned short* __restrict__ yb) {
  int idx = blockIdx.x * blockDim.x + threadIdx.x;
  if (idx >= NB * LSEQ * DI) return;
  yb[idx] = f2bf(yg0[idx] + yg1[idx]);
}

// ======== chunked selective scan: lane = channel, 32 states/wave, LDS B/C broadcast,
// ======== packed-f32 math, launch_bounds(256,4) to keep state out of AGPRs.
// block = 2 chunk-units x 2 half-waves.

__global__ __launch_bounds__(256, 4)
void scan_pass1(const float* __restrict__ dtp_, const float* __restrict__ xi,
                const float* __restrict__ dbl, const float* __restrict__ Alog,
                float* __restrict__ cumdt, float* __restrict__ hendT) {
  __shared__ float Bt[2][CS][64];
  const int tid = threadIdx.x;
  const int wid = tid >> 6, lane = tid & 63;
  const int q = wid >> 1, half = wid & 1;
  const int unit = blockIdx.x * 2 + q;           // over NB*NDG*NCH1
  const int c = unit % NCH1;
  const int bg = unit / NCH1;
  const int b = bg / NDG, dgrp = bg % NDG;
  const int d = dgrp * 64 + lane;
  const int n0 = half * HST;
  const int t0 = c * CS;

  // stage B tile [CS][64] (both halves' states); two waves interleave rows
  {
    const float* srcB = dbl + ((size_t)b * LSEQ + t0) * DBLW + DTR + lane;
    for (int r = half; r < CS; r += 2) Bt[q][r][lane] = srcB[(size_t)r * DBLW];
  }

  f32x2 al2[HST / 2];
  {
    const float4* Ap = (const float4*)(Alog + (size_t)d * NST + n0);
#pragma unroll
    for (int j = 0; j < HST / 4; ++j) {
      float4 v = Ap[j];
      al2[2 * j].x     = -__expf(v.x) * LOG2E;
      al2[2 * j].y     = -__expf(v.y) * LOG2E;
      al2[2 * j + 1].x = -__expf(v.z) * LOG2E;
      al2[2 * j + 1].y = -__expf(v.w) * LOG2E;
    }
  }
  f32x2 h2[HST / 2];
#pragma unroll
  for (int k = 0; k < HST / 2; ++k) h2[k] = (f32x2){0.f, 0.f};

  __syncthreads();

  const float* dtp = dtp_ + ((size_t)b * LSEQ + t0) * DI + d;
  const float* up  = xi   + ((size_t)b * LSEQ + t0) * DI + d;
  float cum = 0.f;
  float dtv = *dtp, uv = *up;
  for (int t = 0; t < CS; ++t) {
    float n_dt = 0.f, n_u = 0.f;
    if (t + 1 < CS) {
      dtp += DI; up += DI;
      n_dt = *dtp; n_u = *up;
    }
    float dtu = dtv * uv;
    f32x2 dt2;  dt2.x = dtv;  dt2.y = dtv;
    f32x2 dtu2; dtu2.x = dtu; dtu2.y = dtu;
#pragma unroll
    for (int k = 0; k < HST / 2; ++k) {
      f32x2 B2 = *(const f32x2*)&Bt[q][t][n0 + 2 * k];   // uniform addr -> broadcast
      f32x2 m2 = pk_mul(dt2, al2[k]);
      f32x2 dA2; dA2.x = exp2f(m2.x); dA2.y = exp2f(m2.y);
      h2[k] = pk_fma(dA2, h2[k], pk_mul(dtu2, B2));
    }
    cum += dtv;
    dtv = n_dt; uv = n_u;
  }
  if (half == 0)
    cumdt[(size_t)bg * NCH1 * 64 + (size_t)c * 64 + lane] = cum;
  float* hp = hendT + ((size_t)bg * NCH1 + c) * NST * 64 + (size_t)n0 * 64 + lane;
#pragma unroll
  for (int k = 0; k < HST / 2; ++k) {
    hp[(2 * k) * 64]     = h2[k].x;
    hp[(2 * k + 1) * 64] = h2[k].y;
  }
}

// pass2: combine chunk summaries. block 256 = 4 waves; block -> bg; wave w -> 16 n's
__global__ __launch_bounds__(256)
void scan_pass2(const float* __restrict__ cumdt, const float* __restrict__ hendT,
                const float* __restrict__ Alog, float* __restrict__ hinitT) {
  int bg = blockIdx.x;
  int lane = threadIdx.x & 63;
  int w = threadIdx.x >> 6;
  int n0 = w * 16;
  int dgrp = bg % NDG;
  int d = dgrp * 64 + lane;

  float al2[16];
#pragma unroll
  for (int j = 0; j < 16; ++j) al2[j] = -__expf(Alog[(size_t)d * NST + n0 + j]) * LOG2E;

  float h[16];
#pragma unroll
  for (int j = 0; j < 16; ++j) h[j] = 0.f;

  for (int c = 0; c < NCH; ++c) {
    float* hi = hinitT + ((size_t)bg * NCH + c) * NST * 64 + (size_t)n0 * 64 + lane;
#pragma unroll
    for (int j = 0; j < 16; ++j) hi[j * 64] = h[j];
    if (c < NCH1) {
      float cum = cumdt[(size_t)bg * NCH1 * 64 + (size_t)c * 64 + lane];
      const float* he = hendT + ((size_t)bg * NCH1 + c) * NST * 64 + (size_t)n0 * 64 + lane;
#pragma unroll
      for (int j = 0; j < 16; ++j) {
        float ap = exp2f(al2[j] * cum);
        h[j] = fmaf(ap, h[j], he[j * 64]);
      }
    }
  }
}

__global__ __launch_bounds__(256, 4)
void scan_pass3(const float* __restrict__ dtp_, const float* __restrict__ xi,
                const float* __restrict__ zg, const float* __restrict__ dbl,
                const float* __restrict__ Alog, const float* __restrict__ Dpar,
                const float* __restrict__ hinitT, float* __restrict__ yg0,
                float* __restrict__ yg1) {
  __shared__ float Bt[2][CS + 1][64];
  __shared__ float Ct[2][CS + 1][64];
  const int tid = threadIdx.x;
  const int wid = tid >> 6, lane = tid & 63;
  const int q = wid >> 1, half = wid & 1;
  const int unit = blockIdx.x * 2 + q;           // over NB*NDG*NCH
  const int c = unit & (NCH - 1);
  const int bg = unit >> 5;
  const int b = bg / NDG, dgrp = bg % NDG;
  const int d = dgrp * 64 + lane;
  const int n0 = half * HST;
  const int t0 = c * CS;
  const int nsteps = (c == NCH - 1) ? (LSEQ - t0) : CS;   // 32 or 33

  // stage: half0 -> B rows, half1 -> C rows
  {
    const float* srcB = dbl + ((size_t)b * LSEQ + t0) * DBLW + DTR + (half ? NST : 0) + lane;
    float* dst = half ? &Ct[q][0][lane] : &Bt[q][0][lane];
    for (int r = 0; r < nsteps; ++r) dst[r * 64] = srcB[(size_t)r * DBLW];
  }

  f32x2 al2[HST / 2];
  {
    const float4* Ap = (const float4*)(Alog + (size_t)d * NST + n0);
#pragma unroll
    for (int j = 0; j < HST / 4; ++j) {
      float4 v = Ap[j];
      al2[2 * j].x     = -__expf(v.x) * LOG2E;
      al2[2 * j].y     = -__expf(v.y) * LOG2E;
      al2[2 * j + 1].x = -__expf(v.z) * LOG2E;
      al2[2 * j + 1].y = -__expf(v.w) * LOG2E;
    }
  }
  float Dp = Dpar[d];
  f32x2 h2[HST / 2];
  {
    const float* hi = hinitT + ((size_t)bg * NCH + c) * NST * 64 + (size_t)n0 * 64 + lane;
#pragma unroll
    for (int k = 0; k < HST / 2; ++k) {
      h2[k].x = hi[(2 * k) * 64];
      h2[k].y = hi[(2 * k + 1) * 64];
    }
  }

  __syncthreads();

  const float* dtp = dtp_ + ((size_t)b * LSEQ + t0) * DI + d;
  const float* up  = xi   + ((size_t)b * LSEQ + t0) * DI + d;
  const float* gp  = zg   + ((size_t)b * LSEQ + t0) * DI + d;
  float* yp = (half == 0 ? yg0 : yg1) + ((size_t)b * LSEQ + t0) * DI + d;

  float dtv = *dtp, uv = *up, gv = *gp;
  for (int t = 0; t < nsteps; ++t) {
    float n_dt = 0.f, n_u = 0.f, n_g = 0.f;
    if (t + 1 < nsteps) {
      dtp += DI; up += DI; gp += DI;
      n_dt = *dtp; n_u = *up; n_g = *gp;
    }
    float dtu = dtv * uv;
    f32x2 dt2;  dt2.x = dtv;  dt2.y = dtv;
    f32x2 dtu2; dtu2.x = dtu; dtu2.y = dtu;
    f32x2 y2 = (f32x2){0.f, 0.f};
#pragma unroll
    for (int k = 0; k < HST / 2; ++k) {
      f32x2 B2 = *(const f32x2*)&Bt[q][t][n0 + 2 * k];
      f32x2 C2 = *(const f32x2*)&Ct[q][t][n0 + 2 * k];
      f32x2 m2 = pk_mul(dt2, al2[k]);
      f32x2 dA2; dA2.x = exp2f(m2.x); dA2.y = exp2f(m2.y);
      h2[k] = pk_fma(dA2, h2[k], pk_mul(dtu2, B2));
      y2 = pk_fma(h2[k], C2, y2);
    }
    float y = y2.x + y2.y;
    float outv = (half == 0) ? fmaf(uv, Dp, y) * gv : y * gv;
    *yp = outv;
    yp += DI;
    dtv = n_dt; uv = n_u; gv = n_g;
  }
}

// ---------------- final norm + masked mean pool + head ------------
__global__ __launch_bounds__(192)
void pool1_kernel(const float* __restrict__ x, const int* __restrict__ mask,
                  const float* __restrict__ fw, float* __restrict__ partial) {
  int b = blockIdx.x >> 6;
  int chunk = blockIdx.x & 63;
  int d = threadIdx.x;
  __shared__ float red[3];
  float w = fw[d];
  float acc = 0.f;
  for (int tt = 0; tt < 16; ++tt) {
    int t = chunk * 16 + tt;
    float v = x[((size_t)b * LSEQ + t) * DM + d];
    float ss = waveReduceSum(v * v);
    if ((d & 63) == 0) red[d >> 6] = ss;
    __syncthreads();
    float ms = (red[0] + red[1] + red[2]) * (1.f / DM);
    float m = (float)mask[b * TSEQ + t];
    acc = fmaf(v * rsqrtf(ms + 1e-6f) * w, m, acc);
    __syncthreads();
  }
  partial[((size_t)b * 64 + chunk) * DM + d] = acc;
}

__global__ __launch_bounds__(192)
void pool2_kernel(const float* __restrict__ partial, const int* __restrict__ mask,
                  const float* __restrict__ hw, const float* __restrict__ hb,
                  float* __restrict__ out) {
  int b = blockIdx.x;
  int d = threadIdx.x;
  float s = 0.f;
  for (int c = 0; c < 64; ++c) s += partial[((size_t)b * 64 + c) * DM + d];
  float den = 0.f;
  for (int t = d; t < TSEQ; t += DM) den += (float)mask[b * TSEQ + t];
  den = waveReduceSum(den);
  __shared__ float dred[3];
  __shared__ float pooled[DM];
  if ((d & 63) == 0) dred[d >> 6] = den;
  __syncthreads();
  float denom = fmaxf(dred[0] + dred[1] + dred[2], 1.f);
  pooled[d] = s / denom;
  __syncthreads();
  if (d < 2) {
    float acc = hb[d];
    for (int k = 0; k < DM; ++k) acc = fmaf(pooled[k], hw[d * DM + k], acc);
    out[b * 2 + d] = acc;
  }
}

}  // namespace

extern "C" void kernel_launch(void* const* d_in, const int* in_sizes, int n_in,
                              void* d_out, int out_size, void* d_ws, size_t ws_size,
                              hipStream_t stream) {
  const int*   ids    = (const int*)d_in[0];
  const int*   mask   = (const int*)d_in[1];
  const float* embed  = (const float*)d_in[2];
  const float* cls    = (const float*)d_in[3];
  const float* norm_w = (const float*)d_in[4];
  const float* in_w   = (const float*)d_in[5];
  const float* conv_w = (const float*)d_in[6];
  const float* conv_b = (const float*)d_in[7];
  const float* xp_w   = (const float*)d_in[8];
  const float* dtw    = (const float*)d_in[9];
  const float* dtb    = (const float*)d_in[10];
  const float* Alog   = (const float*)d_in[11];
  const float* Dpar   = (const float*)d_in[12];
  const float* ow     = (const float*)d_in[13];
  const float* fnw    = (const float*)d_in[14];
  const float* hw     = (const float*)d_in[15];
  const float* hb     = (const float*)d_in[16];
  float* out = (float*)d_out;

  char* base = (char*)d_ws;
  size_t off = 0;
  auto alloc = [&](size_t bytes) -> void* {
    void* p = base + off;
    off = (off + bytes + 255) & ~(size_t)255;
    return p;
  };

  float* x      = (float*)alloc((size_t)NB * LSEQ * DM * 4);
  unsigned short* h16 = (unsigned short*)alloc((size_t)NB * LSEQ * DM * 2);
  float* xz     = (float*)alloc((size_t)NB * LSEQ * DXZ * 4);
  float* xi     = (float*)alloc((size_t)NB * LSEQ * DI * 4);
  unsigned short* xi16 = (unsigned short*)alloc((size_t)NB * LSEQ * DI * 2);
  float* zgbuf  = (float*)alloc((size_t)NB * LSEQ * DI * 4);
  float* dblb   = (float*)alloc((size_t)NB * LSEQ * DBLW * 4);
  float* dtbuf  = (float*)alloc((size_t)NB * LSEQ * DI * 4);
  float* yg0    = (float*)alloc((size_t)NB * LSEQ * DI * 4);
  float* yg1    = (float*)alloc((size_t)NB * LSEQ * DI * 4);
  unsigned short* yb16 = (unsigned short*)alloc((size_t)NB * LSEQ * DI * 2);
  unsigned short* wb_in = (unsigned short*)alloc((size_t)8 * DXZ * DM * 2);
  unsigned short* wb_xp = (unsigned short*)alloc((size_t)8 * XPAD * DI * 2);
  unsigned short* wb_ow = (unsigned short*)alloc((size_t)8 * DM * DI * 2);
  float* wT_dt  = (float*)alloc((size_t)8 * DTR * DI * 4);
  float* partial = (float*)alloc((size_t)NB * 64 * DM * 4);
  float* cumdt  = (float*)alloc((size_t)NB * NDG * NCH1 * 64 * 4);
  float* hendT  = (float*)alloc((size_t)NB * NDG * NCH1 * NST * 64 * 4);
  float* hinitT = (float*)alloc((size_t)NB * NDG * NCH * NST * 64 * 4);

  cvt_bf16_kernel<<<(8 * DXZ * DM + 255) / 256, 256, 0, stream>>>(in_w, wb_in, 8 * DXZ * DM);
  pad_xp_kernel<<<(8 * XPAD * DI + 255) / 256, 256, 0, stream>>>(xp_w, wb_xp);
  cvt_bf16_kernel<<<(8 * DM * DI + 255) / 256, 256, 0, stream>>>(ow, wb_ow, 8 * DM * DI);
  dim3 tb(32, 8);
  transpose_batched<<<dim3(1, 12, 8), tb, 0, stream>>>(dtw, wT_dt, DI, DTR);

  embed_kernel<<<(NB * LSEQ * DM) / 256, 256, 0, stream>>>(ids, embed, cls, x);

  const int mtiles = (MROWS + 127) / 128;  // 65
  for (int l = 0; l < 8; ++l) {
    rmsnorm_kernel<<<MROWS, 192, 0, stream>>>(x, norm_w + l * DM, h16);
    gemm_mfma<0><<<dim3(DXZ / 64, mtiles), 256, 0, stream>>>(
        h16, wb_in + (size_t)l * DXZ * DM, xz, MROWS, DXZ, DXZ, DM, DXZ);
    conv_kernel<<<(NB * LSEQ * DI) / 256, 256, 0, stream>>>(
        xz, conv_w + l * DI * 3, conv_b + l * DI, xi, xi16, zgbuf);
    gemm_mfma<0><<<dim3(XPAD / 64 + 1, mtiles), 256, 0, stream>>>(
        xi16, wb_xp + (size_t)l * XPAD * DI, dblb, MROWS, XPAD, DBLW, DI, DBLW);
    dt_kernel<<<MROWS / 4, DI, 0, stream>>>(dblb, wT_dt + l * DTR * DI, dtb + l * DI, dtbuf);
    // chunked scan
    scan_pass1<<<(NB * NDG * NCH1) / 2, 256, 0, stream>>>(
        dtbuf, xi, dblb, Alog + (size_t)l * DI * NST, cumdt, hendT);
    scan_pass2<<<NB * NDG, 256, 0, stream>>>(
        cumdt, hendT, Alog + (size_t)l * DI * NST, hinitT);
    scan_pass3<<<(NB * NDG * NCH) / 2, 256, 0, stream>>>(
        dtbuf, xi, zgbuf, dblb, Alog + (size_t)l * DI * NST, Dpar + l * DI, hinitT,
        yg0, yg1);
    ysum_kernel<<<(NB * LSEQ * DI + 255) / 256, 256, 0, stream>>>(yg0, yg1, yb16);
    gemm_mfma<1><<<dim3(DM / 64, mtiles), 256, 0, stream>>>(
        yb16, wb_ow + (size_t)l * DM * DI, x, MROWS, DM, DM, DI, DM);
  }

  pool1_kernel<<<NB * 64, 192, 0, stream>>>(x, mask, fnw, partial);
  pool2_kernel<<<NB, 192, 0, stream>>>(partial, mask, hw, hb, out);
}